// Round 15
// baseline (196.052 us; speedup 1.0000x reference)
//
#include <hip/hip_runtime.h>
#include <hip/hip_bf16.h>

typedef unsigned int   u32;
typedef unsigned short u16;

typedef __attribute__((ext_vector_type(8))) short    sh8;
typedef __attribute__((ext_vector_type(4))) float    f32x4;
typedef __attribute__((ext_vector_type(4))) _Float16 f16x4;
typedef __attribute__((ext_vector_type(8))) _Float16 f16x8;
typedef __attribute__((ext_vector_type(2))) _Float16 f16x2;
typedef __attribute__((ext_vector_type(2))) __fp16   fp16x2raw;

union F16x8 { f16x8 v; uint4 u; f16x2 p[4]; _Float16 h[8]; };
union F16x4u { uint2 u; _Float16 h[4]; };
union CvtU  { fp16x2raw r; f16x2 p; u32 u; };

__device__ __forceinline__ float b2f(u16 u) { union { u32 i; float f; } v; v.i = ((u32)u) << 16; return v.f; }
__device__ __forceinline__ u16   f2b(float f){
  union { float f; u32 i; } v; v.f = f;
  u32 u = v.i;
  u32 r = (u + 0x7fffu + ((u >> 16) & 1u)) >> 16;   // RNE
  return (u16)r;
}
// pack two f32 -> bf16x2 (RNE), lo half = a, hi half = b
__device__ __forceinline__ u32 pk2(float a, float b) {
  __hip_bfloat162 h2 = __float22bfloat162_rn(make_float2(a, b));
  union { __hip_bfloat162 h; u32 u; } v; v.h = h2; return v.u;
}
__device__ __forceinline__ f16x2 cvtpk(float a, float b) {
  CvtU c; c.r = __builtin_amdgcn_cvt_pkrtz(a, b); return c.p;
}
__device__ __forceinline__ u32 cvtpku(float a, float b) {
  CvtU c; c.r = __builtin_amdgcn_cvt_pkrtz(a, b); return c.u;
}

__device__ __forceinline__ f32x4 mfma16(uint4 a, uint4 b, f32x4 c) {
  union { uint4 u; sh8 s; } ua, ub;
  ua.u = a; ub.u = b;
  return __builtin_amdgcn_mfma_f32_16x16x32_bf16(ua.s, ub.s, c, 0, 0, 0);
}
__device__ __forceinline__ f32x4 mfma32h(f16x8 a, f16x8 b, f32x4 c) {
  return __builtin_amdgcn_mfma_f32_16x16x32_f16(a, b, c, 0, 0, 0);
}

// split 8 consecutive f32 (one lane's K-chunk) into bf16 hi/lo operand words
__device__ __forceinline__ void split8(float4 v0, float4 v1, uint4& hi, uint4& lo) {
  float a[8] = {v0.x, v0.y, v0.z, v0.w, v1.x, v1.y, v1.z, v1.w};
  u32 hw[4], lw[4];
#pragma unroll
  for (int t = 0; t < 4; t++) {
    u32 hp = pk2(a[2 * t], a[2 * t + 1]);
    float r0 = a[2 * t]     - __uint_as_float(hp << 16);
    float r1 = a[2 * t + 1] - __uint_as_float(hp & 0xffff0000u);
    hw[t] = hp;
    lw[t] = pk2(r0, r1);
  }
  hi = make_uint4(hw[0], hw[1], hw[2], hw[3]);
  lo = make_uint4(lw[0], lw[1], lw[2], lw[3]);
}

// ---------------------------------------------------------------------------
// gemm_mf_pack: QKV projections (N=512, K=256) with FUSED fragment packing.
// by<32: gemm.  n0>=256 -> V stored f16 [b][row][256] (via Ld transpose).
// n0<256 (h = bx): Q/K tile transposed in per-wave LDS, emitted as frags.
// by==32, bx<8: W1 (bf16 hi/lo) + W2 (f16x8 paired-nt mapping) packing.
// by==33: Wout1/Wout2 -> B-operand bf16 hi/lo fragments (for softmax phase C).
// ---------------------------------------------------------------------------
__global__ void __launch_bounds__(256)
gemm_mf_pack(const float* __restrict__ x1, const float* __restrict__ Wqv1, u16* __restrict__ vh1,
             const float* __restrict__ x2, const float* __restrict__ Wkv2, u16* __restrict__ vh2,
             const float* __restrict__ W1, const float* __restrict__ W2,
             const float* __restrict__ Wout1, const float* __restrict__ Wout2,
             uint4* __restrict__ QQ4, uint4* __restrict__ KH4, uint4* __restrict__ KL4z,
             uint4* __restrict__ W1Bhi, uint4* __restrict__ W1Blo,
             uint4* __restrict__ W2F8hi, uint4* __restrict__ W2F8lo,
             uint4* __restrict__ WoHi, uint4* __restrict__ WoLo) {
  __shared__ float Ld[4][16][17];
  int t = threadIdx.x, L = t & 63, w = t >> 6;
  int cl = L & 15, q = L >> 4;
  int by = blockIdx.y;

  if (by == 33) {                       // ---- Wout fragment packing ----
    int tid = blockIdx.x * 256 + t;     // 0..8191
#pragma unroll
    for (int s2 = 0; s2 < 2; s2++) {
      int s = tid + s2 * 8192;
      int dir = s >> 13, rem = s & 8191;
      int nt = rem >> 9, p = (rem >> 6) & 7, LL = rem & 63;
      int ccl = LL & 15, qq = LL >> 4;
      const float* Wo = dir ? Wout2 : Wout1;
      const float* src = Wo + (size_t)(nt * 16 + ccl) * 256 + p * 32 + 8 * qq;
      float4 v0 = *(const float4*)src, v1 = *(const float4*)(src + 4);
      uint4 hi, lo;
      split8(v0, v1, hi, lo);
      size_t idx = (size_t)((dir * 16 + nt) * 8 + p) * 64 + LL;
      WoHi[idx] = hi;
      WoLo[idx] = lo;
    }
    return;
  }

  if (by == 32) {                       // ---- W1/W2 packing blocks ----
    if (blockIdx.x >= 8) return;
    int tid = blockIdx.x * 256 + t;     // 0..2047
    if (tid < 1024) {
      int LL = tid & 63;
      int j = (tid >> 6) * 16 + (LL & 15), qq = LL >> 4;
      u32 hw[4] = {0,0,0,0}, lw[4] = {0,0,0,0};
#pragma unroll
      for (int jj = 0; jj < 8; jj++) {
        float wv = W1[j * 32 + qq * 8 + jj];
        u16 hb = f2b(wv); u16 lb = f2b(wv - b2f(hb));
        hw[jj >> 1] |= ((u32)hb) << (16 * (jj & 1));
        lw[jj >> 1] |= ((u32)lb) << (16 * (jj & 1));
      }
      W1Bhi[tid] = make_uint4(hw[0], hw[1], hw[2], hw[3]);
      W1Blo[tid] = make_uint4(lw[0], lw[1], lw[2], lw[3]);
    } else if (tid < 1536) {
      int t2 = tid - 1024;              // p*64 + L
      int LL = t2 & 63, p = t2 >> 6;
      int h = LL & 15, qq = LL >> 4;
      F16x8 hi, lo;
#pragma unroll
      for (int jj = 0; jj < 8; jj++) {
        int j = 32 * p + ((jj >> 2) << 4) + 4 * qq + (jj & 3);
        float wv = W2[h * 256 + j];
        hi.h[jj] = (_Float16)wv;
        lo.h[jj] = (_Float16)(wv - (float)hi.h[jj]);
      }
      W2F8hi[t2] = hi.u;
      W2F8lo[t2] = lo.u;
    }
    return;
  }

  int sel = by >> 4;
  const float* A  = sel ? x2 : x1;
  const float* Bw = sel ? Wkv2 : Wqv1;
  int m0 = (by & 15) * 64 + w * 16;
  int n0 = blockIdx.x * 16;

  f32x4 acc; acc[0] = 0.f; acc[1] = 0.f; acc[2] = 0.f; acc[3] = 0.f;
  const float* ar = A  + (size_t)(m0 + cl) * 256 + 8 * q;
  const float* br = Bw + (size_t)(n0 + cl) * 256 + 8 * q;

  for (int k0 = 0; k0 < 256; k0 += 32) {
    float4 av0 = *(const float4*)(ar + k0);
    float4 av1 = *(const float4*)(ar + k0 + 4);
    float4 bv0 = *(const float4*)(br + k0);
    float4 bv1 = *(const float4*)(br + k0 + 4);
    uint4 ahi, alo, bhi, blo;
    split8(av0, av1, ahi, alo);
    split8(bv0, bv1, bhi, blo);
    acc = mfma16(ahi, bhi, acc);
    acc = mfma16(ahi, blo, acc);
    acc = mfma16(alo, bhi, acc);
  }

  int b = m0 >> 9;
  int row = (m0 & 511) + cl;            // r (or c) index after transpose

  if (n0 >= 256) {                      // ---- V half: f16 store via transpose ----
#pragma unroll
    for (int i = 0; i < 4; i++) Ld[w][cl][4 * q + i] = acc[i];
    if (q < 2) {
      float v[8];
#pragma unroll
      for (int jj = 0; jj < 8; jj++) v[jj] = Ld[w][q * 8 + jj][cl];
      uint4 o = make_uint4(cvtpku(v[0], v[1]), cvtpku(v[2], v[3]),
                           cvtpku(v[4], v[5]), cvtpku(v[6], v[7]));
      u16* vh = sel ? vh2 : vh1;
      *(uint4*)(vh + ((size_t)(b * 512) + row) * 256 + (n0 - 256) + q * 8) = o;
    }
    return;
  }

  // ---- Q/K half: per-wave 16x16 transpose, then fragment emit ----
#pragma unroll
  for (int i = 0; i < 4; i++) Ld[w][cl][4 * q + i] = acc[i];   // Ld[d][r_local]
  float v[8];
#pragma unroll
  for (int jj = 0; jj < 8; jj++) v[jj] = Ld[w][(q & 1) * 8 + jj][cl];

  int r = row;
  int h = n0 >> 4;                      // == blockIdx.x

  if (sel == 0) {                       // Q: x0.25 folded; q<2 hi, q>=2 lo
    u32 wv[4];
#pragma unroll
    for (int t2 = 0; t2 < 4; t2++) {
      float a  = v[2 * t2] * 0.25f, bb = v[2 * t2 + 1] * 0.25f;
      u32 hp = pk2(a, bb);
      if (q >= 2) {
        float r0 = a  - __uint_as_float(hp << 16);
        float r1 = bb - __uint_as_float(hp & 0xffff0000u);
        wv[t2] = pk2(r0, r1);
      } else wv[t2] = hp;
    }
    QQ4[((size_t)((b * 16 + h) * 4 + q) << 9) + r] = make_uint4(wv[0], wv[1], wv[2], wv[3]);
  } else {                              // K: hi + lo + zero slots
    u32 hw[4], lw[4];
#pragma unroll
    for (int t2 = 0; t2 < 4; t2++) {
      float a = v[2 * t2], bb = v[2 * t2 + 1];
      u32 hp = pk2(a, bb);
      float r0 = a  - __uint_as_float(hp << 16);
      float r1 = bb - __uint_as_float(hp & 0xffff0000u);
      hw[t2] = hp;
      lw[t2] = pk2(r0, r1);
    }
    if (q < 2) {
      KH4[((size_t)((b * 16 + h) * 2 + q) << 9) + r]       = make_uint4(hw[0], hw[1], hw[2], hw[3]);
      KL4z[((size_t)((b * 16 + h) * 4 + 2 + q) << 9) + r]  = make_uint4(0, 0, 0, 0);
    } else {
      KL4z[((size_t)((b * 16 + h) * 4 + (q - 2)) << 9) + r] = make_uint4(lw[0], lw[1], lw[2], lw[3]);
    }
  }
}

// ---------------------------------------------------------------------------
// ms_mfma6 (round-12 champion, verbatim): all-MFMA fused QK^T + MixedScoreFF.
// Layer2 hi and lo of TWO nt-groups fused into single K=32 f16 MFMAs.
// ---------------------------------------------------------------------------
__global__ void __launch_bounds__(256, 2)
ms_mfma6(const uint4* __restrict__ QQ4, const uint4* __restrict__ KH4,
         const uint4* __restrict__ KL4z, const float* __restrict__ cost,
         const uint4* __restrict__ W1Bhi, const uint4* __restrict__ W1Blo,
         const uint4* __restrict__ W2F8hi, const uint4* __restrict__ W2F8lo,
         u16* __restrict__ ms1, u16* __restrict__ ms2) {
  __shared__ __align__(16) u32 Dl[4 * 4160];
  int t = threadIdx.x, L = t & 63, w = t >> 6;
  int cl = L & 15, q = L >> 4;
  int b = blockIdx.z, c0 = blockIdx.x * 16, r0 = (blockIdx.y * 4 + w) * 16;
  u32* D = Dl + w * 4160;

  f32x4 z; z[0] = 0.f; z[1] = 0.f; z[2] = 0.f; z[3] = 0.f;

  // ---- phase A: QK^T (scaled) via MFMA, 16 heads -> D[h][r][c] in LDS ----
#pragma unroll 2
  for (int h = 0; h < 16; h++) {
    uint4 qa  = QQ4[((size_t)((b * 16 + h) * 4 + q) << 9) + r0 + cl];       // [qh|ql]
    uint4 qa2 = QQ4[((size_t)((b * 16 + h) * 4 + (q & 1)) << 9) + r0 + cl]; // [qh|qh]
    uint4 kb1 = KH4[((size_t)((b * 16 + h) * 2 + (q & 1)) << 9) + c0 + cl]; // [kh|kh]
    uint4 kb2 = KL4z[((size_t)((b * 16 + h) * 4 + q) << 9) + c0 + cl];      // [kl|0]
    f32x4 d = mfma16(qa, kb1, z);
    d = mfma16(qa2, kb2, d);
#pragma unroll
    for (int i = 0; i < 4; i++)
      D[h * 260 + (q * 4 + i) * 16 + cl] = __float_as_uint(d[i]);
  }

  // ---- phase A2: build X fragments (B-operand: n=cell=cl, k=8q+idx) ----
  uint4 xhi[16], xlo[16];
#pragma unroll
  for (int r = 0; r < 16; r++) {
    float cvm = cost[((size_t)(b * 512) + r0 + r) * 512 + c0 + cl];
    u32 cp = pk2(cvm, cvm);
    float cres = cvm - __uint_as_float(cp & 0xffff0000u);
    u32 hw[4], lw[4];
#pragma unroll
    for (int tt = 0; tt < 4; tt++) {
      float dd = __uint_as_float(D[(4 * q + tt) * 260 + r * 16 + cl]);
      u32 hp = pk2(dd, cvm);
      float dres = dd - __uint_as_float(hp << 16);
      hw[tt] = hp;
      lw[tt] = pk2(dres, cres);
    }
    xhi[r] = make_uint4(hw[0], hw[1], hw[2], hw[3]);
    xlo[r] = make_uint4(lw[0], lw[1], lw[2], lw[3]);
  }

  // ---- phase B: p-outer MLP over nt-pairs (nt = 2p, 2p+1) ----
  f32x4 acc2[16];
#pragma unroll
  for (int r = 0; r < 16; r++) acc2[r] = z;

#pragma unroll 1
  for (int p = 0; p < 8; p++) {
    uint4 w1h0 = W1Bhi[(2 * p) * 64 + L],     w1l0 = W1Blo[(2 * p) * 64 + L];
    uint4 w1h1 = W1Bhi[(2 * p + 1) * 64 + L], w1l1 = W1Blo[(2 * p + 1) * 64 + L];
    F16x8 w2h, w2l;
    w2h.u = W2F8hi[p * 64 + L];
    w2l.u = W2F8lo[p * 64 + L];
#pragma unroll
    for (int r = 0; r < 16; r++) {
      f32x4 a0 = z, a1 = z;
      a0 = mfma16(w1h0, xhi[r], a0);
      a0 = mfma16(w1h0, xlo[r], a0);
      a0 = mfma16(w1l0, xhi[r], a0);
      a1 = mfma16(w1h1, xhi[r], a1);
      a1 = mfma16(w1h1, xlo[r], a1);
      a1 = mfma16(w1l1, xhi[r], a1);
      F16x8 hf;
      hf.p[0] = cvtpk(fmaxf(a0[0], 0.f), fmaxf(a0[1], 0.f));
      hf.p[1] = cvtpk(fmaxf(a0[2], 0.f), fmaxf(a0[3], 0.f));
      hf.p[2] = cvtpk(fmaxf(a1[0], 0.f), fmaxf(a1[1], 0.f));
      hf.p[3] = cvtpk(fmaxf(a1[2], 0.f), fmaxf(a1[3], 0.f));
      acc2[r] = mfma32h(hf.v, w2h.v, acc2[r]);
      acc2[r] = mfma32h(hf.v, w2l.v, acc2[r]);
    }
  }

  // ---- epilogue: lane (q,cl) holds MS[h=cl][c=c0+4q+i][r0..r0+15] ----
  u32* ms1u = (u32*)ms1;
#pragma unroll
  for (int r = 0; r < 16; r++) {
    size_t base = ((size_t)(b * 16 + cl) * 512 + (r0 + r)) * 256 + (c0 >> 1) + q * 2;
    ms1u[base]     = pk2(acc2[r][0], acc2[r][1]);
    ms1u[base + 1] = pk2(acc2[r][2], acc2[r][3]);
  }
  u32* ms2u = (u32*)ms2;
#pragma unroll
  for (int i = 0; i < 4; i++) {
    int c = c0 + 4 * q + i;
    u32 o[8];
#pragma unroll
    for (int rr = 0; rr < 8; rr++)
      o[rr] = pk2(acc2[2 * rr][i], acc2[2 * rr + 1][i]);
    size_t base2 = ((size_t)(b * 16 + cl) * 512 + c) * 256 + (r0 >> 1);
    *(uint4*)&ms2u[base2]     = make_uint4(o[0], o[1], o[2], o[3]);
    *(uint4*)&ms2u[base2 + 4] = make_uint4(o[4], o[5], o[6], o[7]);
  }
}

// ---------------------------------------------------------------------------
// softmax_all6: softmax + weighted-V + FUSED output projection.
// Block = (b, 4 fix rows, dir).  Phase A: masked softmax (p f16, swizzled
// LDS).  Phase B: f16 V accumulation.  Phase C: o rows (LDS, padded 260)
// @ Wout^T via MFMA with precomputed B-fragments -> writes d_out directly.
// ---------------------------------------------------------------------------
__global__ void __launch_bounds__(256)
softmax_all6(const u16* __restrict__ ms1s, const u16* __restrict__ ms2s,
             const int* __restrict__ mask,
             const u16* __restrict__ vh1, const u16* __restrict__ vh2,
             const uint4* __restrict__ WoHi, const uint4* __restrict__ WoLo,
             float* __restrict__ out) {
  __shared__ _Float16 pbuf[512 * 16 * 4];   // [cc][(h+cc)&15][f]  64 KB
  __shared__ float    sden[4][16];
  __shared__ float4   red[4][64];
  __shared__ float    obuf_l[4][260];       // o rows, padded stride
  int t = threadIdx.x, lane = t & 63, w = t >> 6;
  int fix0 = blockIdx.x * 4, b = blockIdx.y, dir = blockIdx.z;
  const u16* ms   = dir ? ms2s : ms1s;
  const u16* vbuf = dir ? vh1 : vh2;
  float*     outp = dir ? out + 262144 : out;

  // ---- phase A: wave w handles fix = fix0 + w ----
  int fix = fix0 + w;
  bool vd[8];
#pragma unroll
  for (int i = 0; i < 8; i++) {
    int cc = i * 64 + lane;
    int mv = dir ? mask[((size_t)b * 512 + cc) * 512 + fix]
                 : mask[((size_t)b * 512 + fix) * 512 + cc];
    vd[i] = mv != 0;
  }
  bool anyl = false;
#pragma unroll
  for (int i = 0; i < 8; i++) anyl |= vd[i];
  bool useMask = (__ballot(anyl) != 0ULL);   // fully-masked row => unmask all

#pragma unroll 2
  for (int h = 0; h < 16; h++) {
    const u16* mrow = ms + ((size_t)(b * 16 + h) * 512 + fix) * 512;
    float lg[8];
#pragma unroll
    for (int i = 0; i < 8; i++) lg[i] = b2f(mrow[i * 64 + lane]);
    float mx = -3.4e38f;
#pragma unroll
    for (int i = 0; i < 8; i++)
      if (!(useMask && !vd[i])) mx = fmaxf(mx, lg[i]);
    for (int off = 32; off; off >>= 1) mx = fmaxf(mx, __shfl_xor(mx, off));
    float s = 0.f;
#pragma unroll
    for (int i = 0; i < 8; i++) {
      float p = (useMask && !vd[i]) ? 0.f : __expf(lg[i] - mx);
      int cc = i * 64 + lane;
      pbuf[(cc * 16 + ((h + cc) & 15)) * 4 + w] = (_Float16)p;
      s += p;
    }
    for (int off = 32; off; off >>= 1) s += __shfl_xor(s, off);
    if (lane == 0) sden[w][h] = s;
  }
  __syncthreads();

  // ---- phase B: thread (w, hb=lane>>2, dq=lane&3) accumulates cc = 4*it+w ----
  int hb = lane >> 2, dq = lane & 3;
  const u16* vb = vbuf + (size_t)b * 131072 + hb * 16 + dq * 4;
  float4 acc[4];
#pragma unroll
  for (int f = 0; f < 4; f++) acc[f] = make_float4(0.f, 0.f, 0.f, 0.f);
  for (int it = 0; it < 128; it++) {
    int cc = it * 4 + w;
    F16x4u vv; vv.u = *(const uint2*)(vb + (size_t)cc * 256);
    F16x4u pv; pv.u = *(const uint2*)&pbuf[(cc * 16 + ((hb + cc) & 15)) * 4];
    float v0 = (float)vv.h[0], v1 = (float)vv.h[1];
    float v2 = (float)vv.h[2], v3 = (float)vv.h[3];
#pragma unroll
    for (int f = 0; f < 4; f++) {
      float p = (float)pv.h[f];
      acc[f].x += p * v0; acc[f].y += p * v1;
      acc[f].z += p * v2; acc[f].w += p * v3;
    }
  }
#pragma unroll 1
  for (int f = 0; f < 4; f++) {
    red[w][lane] = acc[f];
    __syncthreads();
    if (w == 0) {
      float4 s0 = red[0][lane], s1 = red[1][lane];
      float4 s2 = red[2][lane], s3 = red[3][lane];
      float inv = 1.f / sden[f][hb];
      obuf_l[f][lane * 4 + 0] = (s0.x + s1.x + s2.x + s3.x) * inv;
      obuf_l[f][lane * 4 + 1] = (s0.y + s1.y + s2.y + s3.y) * inv;
      obuf_l[f][lane * 4 + 2] = (s0.z + s1.z + s2.z + s3.z) * inv;
      obuf_l[f][lane * 4 + 3] = (s0.w + s1.w + s2.w + s3.w) * inv;
    }
    __syncthreads();
  }

  // ---- phase C: out rows = obuf_l @ Wout^T via MFMA ----
  int cl2 = lane & 15, q2 = lane >> 4;
  uint4 ahi[8], alo[8];
#pragma unroll
  for (int p = 0; p < 8; p++) {
    float4 a0v, a1v;
    if (cl2 < 4) {
      a0v = *(const float4*)&obuf_l[cl2][p * 32 + 8 * q2];
      a1v = *(const float4*)&obuf_l[cl2][p * 32 + 8 * q2 + 4];
    } else {
      a0v = make_float4(0.f, 0.f, 0.f, 0.f);
      a1v = make_float4(0.f, 0.f, 0.f, 0.f);
    }
    split8(a0v, a1v, ahi[p], alo[p]);
  }
  f32x4 z; z[0] = 0.f; z[1] = 0.f; z[2] = 0.f; z[3] = 0.f;
#pragma unroll
  for (int j = 0; j < 4; j++) {
    int nt = w * 4 + j;
    f32x4 a2 = z;
#pragma unroll 1
    for (int p = 0; p < 8; p++) {
      size_t idx = (size_t)((dir * 16 + nt) * 8 + p) * 64 + lane;
      uint4 bhi = WoHi[idx];
      uint4 blo = WoLo[idx];
      a2 = mfma16(ahi[p], bhi, a2);
      a2 = mfma16(ahi[p], blo, a2);
      a2 = mfma16(alo[p], bhi, a2);
    }
    if (lane < 16) {                    // q==0 lanes hold rows 0..3 = fixes
#pragma unroll
      for (int i = 0; i < 4; i++)
        outp[((size_t)b * 512 + fix0 + i) * 256 + nt * 16 + lane] = a2[i];
    }
  }
}

// ---------------------------------------------------------------------------
extern "C" void kernel_launch(void* const* d_in, const int* in_sizes, int n_in,
                              void* d_out, int out_size, void* d_ws, size_t ws_size,
                              hipStream_t stream) {
  const float* x1    = (const float*)d_in[0];
  const float* x2    = (const float*)d_in[1];
  const int*   attn  = (const int*)d_in[2];
  const float* cost  = (const float*)d_in[3];
  const float* Wqv1  = (const float*)d_in[4];
  const float* Wkv2  = (const float*)d_in[5];
  const float* W1    = (const float*)d_in[6];
  const float* W2    = (const float*)d_in[7];
  const float* Wout1 = (const float*)d_in[8];
  const float* Wout2 = (const float*)d_in[9];
  float* out = (float*)d_out;

  char* ws = (char*)d_ws;
  uint4* W1Bhi  = (uint4*)(ws);                              // 16 KB
  uint4* W1Blo  = (uint4*)(ws + (16 << 10));                 // 16 KB
  uint4* W2F8hi = (uint4*)(ws + (32 << 10));                 //  8 KB
  uint4* W2F8lo = (uint4*)(ws + (40 << 10));                 //  8 KB
  u16*   vh1 = (u16*)(ws + (64 << 10));                      // 512 KB [b][r][256] f16 (v1)
  u16*   vh2 = (u16*)(ws + (64 << 10) + (512 << 10));        // 512 KB [b][c][256] f16 (v2)
  u16*   ms1 = (u16*)(ws + (64 << 10) + (4 << 20));          //  16 MB [b][h][r][c]
  u16*   ms2 = (u16*)(ws + (64 << 10) + (20 << 20));         //  16 MB [b][h][c][r]
  char*  tail= (ws + (64 << 10) + (36 << 20));
  uint4* QQ4  = (uint4*)(tail);                              //   1 MB
  uint4* KH4  = (uint4*)(tail + (1 << 20));                  // 0.5 MB
  uint4* KL4z = (uint4*)(tail + (1 << 20) + (512 << 10));    //   1 MB
  uint4* WoHi = (uint4*)(tail + (1 << 20) + (512 << 10) + (1 << 20));      // 256 KB
  uint4* WoLo = (uint4*)(tail + (1 << 20) + (512 << 10) + (1 << 20) + (256 << 10)); // 256 KB

  gemm_mf_pack<<<dim3(32, 34), 256, 0, stream>>>(x1, Wqv1, vh1, x2, Wkv2, vh2,
                                                 W1, W2, Wout1, Wout2,
                                                 QQ4, KH4, KL4z,
                                                 W1Bhi, W1Blo, W2F8hi, W2F8lo,
                                                 WoHi, WoLo);

  ms_mfma6<<<dim3(32, 8, 2), 256, 0, stream>>>(QQ4, KH4, KL4z, cost,
                                               W1Bhi, W1Blo, W2F8hi, W2F8lo, ms1, ms2);

  softmax_all6<<<dim3(128, 2, 2), 256, 0, stream>>>(ms1, ms2, attn, vh1, vh2,
                                                    WoHi, WoLo, out);
}

// Round 16
// 171.760 us; speedup vs baseline: 1.1414x; 1.1414x over previous
//
#include <hip/hip_runtime.h>
#include <hip/hip_bf16.h>

typedef unsigned int   u32;
typedef unsigned short u16;

typedef __attribute__((ext_vector_type(8))) short    sh8;
typedef __attribute__((ext_vector_type(4))) float    f32x4;
typedef __attribute__((ext_vector_type(4))) _Float16 f16x4;
typedef __attribute__((ext_vector_type(8))) _Float16 f16x8;
typedef __attribute__((ext_vector_type(2))) _Float16 f16x2;
typedef __attribute__((ext_vector_type(2))) __fp16   fp16x2raw;

union F16x8 { f16x8 v; uint4 u; f16x2 p[4]; _Float16 h[8]; };
union F16x4u { uint2 u; _Float16 h[4]; };
union F16x2u { u32 u; _Float16 h[2]; };
union CvtU  { fp16x2raw r; f16x2 p; u32 u; };

__device__ __forceinline__ float b2f(u16 u) { union { u32 i; float f; } v; v.i = ((u32)u) << 16; return v.f; }
__device__ __forceinline__ u16   f2b(float f){
  union { float f; u32 i; } v; v.f = f;
  u32 u = v.i;
  u32 r = (u + 0x7fffu + ((u >> 16) & 1u)) >> 16;   // RNE
  return (u16)r;
}
// pack two f32 -> bf16x2 (RNE), lo half = a, hi half = b
__device__ __forceinline__ u32 pk2(float a, float b) {
  __hip_bfloat162 h2 = __float22bfloat162_rn(make_float2(a, b));
  union { __hip_bfloat162 h; u32 u; } v; v.h = h2; return v.u;
}
__device__ __forceinline__ f16x2 cvtpk(float a, float b) {
  CvtU c; c.r = __builtin_amdgcn_cvt_pkrtz(a, b); return c.p;
}
__device__ __forceinline__ u32 cvtpku(float a, float b) {
  CvtU c; c.r = __builtin_amdgcn_cvt_pkrtz(a, b); return c.u;
}

__device__ __forceinline__ f32x4 mfma16(uint4 a, uint4 b, f32x4 c) {
  union { uint4 u; sh8 s; } ua, ub;
  ua.u = a; ub.u = b;
  return __builtin_amdgcn_mfma_f32_16x16x32_bf16(ua.s, ub.s, c, 0, 0, 0);
}
__device__ __forceinline__ f32x4 mfma32h(f16x8 a, f16x8 b, f32x4 c) {
  return __builtin_amdgcn_mfma_f32_16x16x32_f16(a, b, c, 0, 0, 0);
}

// split 8 consecutive f32 (one lane's K-chunk) into bf16 hi/lo operand words
__device__ __forceinline__ void split8(float4 v0, float4 v1, uint4& hi, uint4& lo) {
  float a[8] = {v0.x, v0.y, v0.z, v0.w, v1.x, v1.y, v1.z, v1.w};
  u32 hw[4], lw[4];
#pragma unroll
  for (int t = 0; t < 4; t++) {
    u32 hp = pk2(a[2 * t], a[2 * t + 1]);
    float r0 = a[2 * t]     - __uint_as_float(hp << 16);
    float r1 = a[2 * t + 1] - __uint_as_float(hp & 0xffff0000u);
    hw[t] = hp;
    lw[t] = pk2(r0, r1);
  }
  hi = make_uint4(hw[0], hw[1], hw[2], hw[3]);
  lo = make_uint4(lw[0], lw[1], lw[2], lw[3]);
}

// ---------------------------------------------------------------------------
// gemm_mf: two independent C = A @ B^T f32 GEMMs via MFMA (sel = by>>4).
// One wave per 16x16 C tile.  Used for the output projections (N=256, K=256).
// ---------------------------------------------------------------------------
__global__ void __launch_bounds__(256)
gemm_mf(const float* __restrict__ A0, const float* __restrict__ B0, float* __restrict__ C0,
        const float* __restrict__ A1, const float* __restrict__ B1, float* __restrict__ C1,
        int N, int K) {
  int t = threadIdx.x, L = t & 63, w = t >> 6;
  int cl = L & 15, q = L >> 4;
  int by = blockIdx.y, sel = by >> 4;
  const float* A  = sel ? A1 : A0;
  const float* Bw = sel ? B1 : B0;
  float*       C  = sel ? C1 : C0;
  int m0 = (by & 15) * 64 + w * 16;
  int n0 = blockIdx.x * 16;

  f32x4 acc; acc[0] = 0.f; acc[1] = 0.f; acc[2] = 0.f; acc[3] = 0.f;
  const float* ar = A  + (size_t)(m0 + cl) * K + 8 * q;
  const float* br = Bw + (size_t)(n0 + cl) * K + 8 * q;

  for (int k0 = 0; k0 < K; k0 += 32) {
    float4 av0 = *(const float4*)(ar + k0);
    float4 av1 = *(const float4*)(ar + k0 + 4);
    float4 bv0 = *(const float4*)(br + k0);
    float4 bv1 = *(const float4*)(br + k0 + 4);
    uint4 ahi, alo, bhi, blo;
    split8(av0, av1, ahi, alo);
    split8(bv0, bv1, bhi, blo);
    acc = mfma16(ahi, bhi, acc);
    acc = mfma16(ahi, blo, acc);
    acc = mfma16(alo, bhi, acc);
  }
#pragma unroll
  for (int i = 0; i < 4; i++)
    C[(size_t)(m0 + 4 * q + i) * N + n0 + cl] = acc[i];
}

// ---------------------------------------------------------------------------
// gemm_mf_pack: QKV projections (N=512, K=256) with FUSED fragment packing.
// by<32: gemm.  n0>=256 -> V stored f16 [b][row][256] (via Ld transpose).
// n0<256 (h = bx): Q/K tile transposed in per-wave LDS, emitted as frags.
// by==32, bx<8: W1 (bf16 hi/lo) + W2 (f16x8 paired-nt mapping) packing.
// ---------------------------------------------------------------------------
__global__ void __launch_bounds__(256)
gemm_mf_pack(const float* __restrict__ x1, const float* __restrict__ Wqv1, u16* __restrict__ vh1,
             const float* __restrict__ x2, const float* __restrict__ Wkv2, u16* __restrict__ vh2,
             const float* __restrict__ W1, const float* __restrict__ W2,
             uint4* __restrict__ QQ4, uint4* __restrict__ KH4, uint4* __restrict__ KL4z,
             uint4* __restrict__ W1Bhi, uint4* __restrict__ W1Blo,
             uint4* __restrict__ W2F8hi, uint4* __restrict__ W2F8lo) {
  __shared__ float Ld[4][16][17];
  int t = threadIdx.x, L = t & 63, w = t >> 6;
  int cl = L & 15, q = L >> 4;
  int by = blockIdx.y;

  if (by == 32) {                       // ---- W packing blocks ----
    if (blockIdx.x >= 8) return;
    int tid = blockIdx.x * 256 + t;     // 0..2047
    if (tid < 1024) {
      int LL = tid & 63;
      int j = (tid >> 6) * 16 + (LL & 15), qq = LL >> 4;
      u32 hw[4] = {0,0,0,0}, lw[4] = {0,0,0,0};
#pragma unroll
      for (int jj = 0; jj < 8; jj++) {
        float wv = W1[j * 32 + qq * 8 + jj];
        u16 hb = f2b(wv); u16 lb = f2b(wv - b2f(hb));
        hw[jj >> 1] |= ((u32)hb) << (16 * (jj & 1));
        lw[jj >> 1] |= ((u32)lb) << (16 * (jj & 1));
      }
      W1Bhi[tid] = make_uint4(hw[0], hw[1], hw[2], hw[3]);
      W1Blo[tid] = make_uint4(lw[0], lw[1], lw[2], lw[3]);
    } else if (tid < 1536) {
      int t2 = tid - 1024;              // p*64 + L
      int LL = t2 & 63, p = t2 >> 6;
      int h = LL & 15, qq = LL >> 4;
      F16x8 hi, lo;
#pragma unroll
      for (int jj = 0; jj < 8; jj++) {
        int j = 32 * p + ((jj >> 2) << 4) + 4 * qq + (jj & 3);
        float wv = W2[h * 256 + j];
        hi.h[jj] = (_Float16)wv;
        lo.h[jj] = (_Float16)(wv - (float)hi.h[jj]);
      }
      W2F8hi[t2] = hi.u;
      W2F8lo[t2] = lo.u;
    }
    return;
  }

  int sel = by >> 4;
  const float* A  = sel ? x2 : x1;
  const float* Bw = sel ? Wkv2 : Wqv1;
  int m0 = (by & 15) * 64 + w * 16;
  int n0 = blockIdx.x * 16;

  f32x4 acc; acc[0] = 0.f; acc[1] = 0.f; acc[2] = 0.f; acc[3] = 0.f;
  const float* ar = A  + (size_t)(m0 + cl) * 256 + 8 * q;
  const float* br = Bw + (size_t)(n0 + cl) * 256 + 8 * q;

  for (int k0 = 0; k0 < 256; k0 += 32) {
    float4 av0 = *(const float4*)(ar + k0);
    float4 av1 = *(const float4*)(ar + k0 + 4);
    float4 bv0 = *(const float4*)(br + k0);
    float4 bv1 = *(const float4*)(br + k0 + 4);
    uint4 ahi, alo, bhi, blo;
    split8(av0, av1, ahi, alo);
    split8(bv0, bv1, bhi, blo);
    acc = mfma16(ahi, bhi, acc);
    acc = mfma16(ahi, blo, acc);
    acc = mfma16(alo, bhi, acc);
  }

  int b = m0 >> 9;
  int row = (m0 & 511) + cl;            // r (or c) index after transpose

  if (n0 >= 256) {                      // ---- V half: f16 store via transpose ----
#pragma unroll
    for (int i = 0; i < 4; i++) Ld[w][cl][4 * q + i] = acc[i];
    if (q < 2) {
      float v[8];
#pragma unroll
      for (int jj = 0; jj < 8; jj++) v[jj] = Ld[w][q * 8 + jj][cl];
      uint4 o = make_uint4(cvtpku(v[0], v[1]), cvtpku(v[2], v[3]),
                           cvtpku(v[4], v[5]), cvtpku(v[6], v[7]));
      u16* vh = sel ? vh2 : vh1;
      *(uint4*)(vh + ((size_t)(b * 512) + row) * 256 + (n0 - 256) + q * 8) = o;
    }
    return;
  }

  // ---- Q/K half: per-wave 16x16 transpose, then fragment emit ----
#pragma unroll
  for (int i = 0; i < 4; i++) Ld[w][cl][4 * q + i] = acc[i];   // Ld[d][r_local]
  float v[8];
#pragma unroll
  for (int jj = 0; jj < 8; jj++) v[jj] = Ld[w][(q & 1) * 8 + jj][cl];

  int r = row;
  int h = n0 >> 4;                      // == blockIdx.x

  if (sel == 0) {                       // Q: x0.25 folded; q<2 hi, q>=2 lo
    u32 wv[4];
#pragma unroll
    for (int t2 = 0; t2 < 4; t2++) {
      float a  = v[2 * t2] * 0.25f, bb = v[2 * t2 + 1] * 0.25f;
      u32 hp = pk2(a, bb);
      if (q >= 2) {
        float r0 = a  - __uint_as_float(hp << 16);
        float r1 = bb - __uint_as_float(hp & 0xffff0000u);
        wv[t2] = pk2(r0, r1);
      } else wv[t2] = hp;
    }
    QQ4[((size_t)((b * 16 + h) * 4 + q) << 9) + r] = make_uint4(wv[0], wv[1], wv[2], wv[3]);
  } else {                              // K: hi + lo + zero slots
    u32 hw[4], lw[4];
#pragma unroll
    for (int t2 = 0; t2 < 4; t2++) {
      float a = v[2 * t2], bb = v[2 * t2 + 1];
      u32 hp = pk2(a, bb);
      float r0 = a  - __uint_as_float(hp << 16);
      float r1 = bb - __uint_as_float(hp & 0xffff0000u);
      hw[t2] = hp;
      lw[t2] = pk2(r0, r1);
    }
    if (q < 2) {
      KH4[((size_t)((b * 16 + h) * 2 + q) << 9) + r]       = make_uint4(hw[0], hw[1], hw[2], hw[3]);
      KL4z[((size_t)((b * 16 + h) * 4 + 2 + q) << 9) + r]  = make_uint4(0, 0, 0, 0);
    } else {
      KL4z[((size_t)((b * 16 + h) * 4 + (q - 2)) << 9) + r] = make_uint4(lw[0], lw[1], lw[2], lw[3]);
    }
  }
}

// ---------------------------------------------------------------------------
// ms_mfma6 (round-12 champion, verbatim): all-MFMA fused QK^T + MixedScoreFF.
// ---------------------------------------------------------------------------
__global__ void __launch_bounds__(256, 2)
ms_mfma6(const uint4* __restrict__ QQ4, const uint4* __restrict__ KH4,
         const uint4* __restrict__ KL4z, const float* __restrict__ cost,
         const uint4* __restrict__ W1Bhi, const uint4* __restrict__ W1Blo,
         const uint4* __restrict__ W2F8hi, const uint4* __restrict__ W2F8lo,
         u16* __restrict__ ms1, u16* __restrict__ ms2) {
  __shared__ __align__(16) u32 Dl[4 * 4160];
  int t = threadIdx.x, L = t & 63, w = t >> 6;
  int cl = L & 15, q = L >> 4;
  int b = blockIdx.z, c0 = blockIdx.x * 16, r0 = (blockIdx.y * 4 + w) * 16;
  u32* D = Dl + w * 4160;

  f32x4 z; z[0] = 0.f; z[1] = 0.f; z[2] = 0.f; z[3] = 0.f;

#pragma unroll 2
  for (int h = 0; h < 16; h++) {
    uint4 qa  = QQ4[((size_t)((b * 16 + h) * 4 + q) << 9) + r0 + cl];
    uint4 qa2 = QQ4[((size_t)((b * 16 + h) * 4 + (q & 1)) << 9) + r0 + cl];
    uint4 kb1 = KH4[((size_t)((b * 16 + h) * 2 + (q & 1)) << 9) + c0 + cl];
    uint4 kb2 = KL4z[((size_t)((b * 16 + h) * 4 + q) << 9) + c0 + cl];
    f32x4 d = mfma16(qa, kb1, z);
    d = mfma16(qa2, kb2, d);
#pragma unroll
    for (int i = 0; i < 4; i++)
      D[h * 260 + (q * 4 + i) * 16 + cl] = __float_as_uint(d[i]);
  }

  uint4 xhi[16], xlo[16];
#pragma unroll
  for (int r = 0; r < 16; r++) {
    float cvm = cost[((size_t)(b * 512) + r0 + r) * 512 + c0 + cl];
    u32 cp = pk2(cvm, cvm);
    float cres = cvm - __uint_as_float(cp & 0xffff0000u);
    u32 hw[4], lw[4];
#pragma unroll
    for (int tt = 0; tt < 4; tt++) {
      float dd = __uint_as_float(D[(4 * q + tt) * 260 + r * 16 + cl]);
      u32 hp = pk2(dd, cvm);
      float dres = dd - __uint_as_float(hp << 16);
      hw[tt] = hp;
      lw[tt] = pk2(dres, cres);
    }
    xhi[r] = make_uint4(hw[0], hw[1], hw[2], hw[3]);
    xlo[r] = make_uint4(lw[0], lw[1], lw[2], lw[3]);
  }

  f32x4 acc2[16];
#pragma unroll
  for (int r = 0; r < 16; r++) acc2[r] = z;

#pragma unroll 1
  for (int p = 0; p < 8; p++) {
    uint4 w1h0 = W1Bhi[(2 * p) * 64 + L],     w1l0 = W1Blo[(2 * p) * 64 + L];
    uint4 w1h1 = W1Bhi[(2 * p + 1) * 64 + L], w1l1 = W1Blo[(2 * p + 1) * 64 + L];
    F16x8 w2h, w2l;
    w2h.u = W2F8hi[p * 64 + L];
    w2l.u = W2F8lo[p * 64 + L];
#pragma unroll
    for (int r = 0; r < 16; r++) {
      f32x4 a0 = z, a1 = z;
      a0 = mfma16(w1h0, xhi[r], a0);
      a0 = mfma16(w1h0, xlo[r], a0);
      a0 = mfma16(w1l0, xhi[r], a0);
      a1 = mfma16(w1h1, xhi[r], a1);
      a1 = mfma16(w1h1, xlo[r], a1);
      a1 = mfma16(w1l1, xhi[r], a1);
      F16x8 hf;
      hf.p[0] = cvtpk(fmaxf(a0[0], 0.f), fmaxf(a0[1], 0.f));
      hf.p[1] = cvtpk(fmaxf(a0[2], 0.f), fmaxf(a0[3], 0.f));
      hf.p[2] = cvtpk(fmaxf(a1[0], 0.f), fmaxf(a1[1], 0.f));
      hf.p[3] = cvtpk(fmaxf(a1[2], 0.f), fmaxf(a1[3], 0.f));
      acc2[r] = mfma32h(hf.v, w2h.v, acc2[r]);
      acc2[r] = mfma32h(hf.v, w2l.v, acc2[r]);
    }
  }

  u32* ms1u = (u32*)ms1;
#pragma unroll
  for (int r = 0; r < 16; r++) {
    size_t base = ((size_t)(b * 16 + cl) * 512 + (r0 + r)) * 256 + (c0 >> 1) + q * 2;
    ms1u[base]     = pk2(acc2[r][0], acc2[r][1]);
    ms1u[base + 1] = pk2(acc2[r][2], acc2[r][3]);
  }
  u32* ms2u = (u32*)ms2;
#pragma unroll
  for (int i = 0; i < 4; i++) {
    int c = c0 + 4 * q + i;
    u32 o[8];
#pragma unroll
    for (int rr = 0; rr < 8; rr++)
      o[rr] = pk2(acc2[2 * rr][i], acc2[2 * rr + 1][i]);
    size_t base2 = ((size_t)(b * 16 + cl) * 512 + c) * 256 + (r0 >> 1);
    *(uint4*)&ms2u[base2]     = make_uint4(o[0], o[1], o[2], o[3]);
    *(uint4*)&ms2u[base2 + 4] = make_uint4(o[4], o[5], o[6], o[7]);
  }
}

// ---------------------------------------------------------------------------
// softmax_all5b: 2 fixes per block for 2x occupancy (~37 KB LDS -> 4 blk/CU;
// R15 evidence: softmax family latency-bound at 2 blk/CU, both pipes idle).
// Wave w handles fix = fix0 + (w>>1), heads (w&1)*8..+7.  p stored f16 in
// swizzled LDS [cc][(h+cc)&15][f2]; phase B reads one u32 = both fixes.
// ---------------------------------------------------------------------------
__global__ void __launch_bounds__(256)
softmax_all5b(const u16* __restrict__ ms1s, const u16* __restrict__ ms2s,
              const int* __restrict__ mask,
              const u16* __restrict__ vh1, const u16* __restrict__ vh2,
              float* __restrict__ o1, float* __restrict__ o2) {
  __shared__ _Float16 pbuf[512 * 16 * 2];   // 32 KB
  __shared__ float    sden[2][16];
  __shared__ float4   red[4][64];
  int t = threadIdx.x, lane = t & 63, w = t >> 6;
  int fix0 = blockIdx.x * 2, b = blockIdx.y, dir = blockIdx.z;
  const u16* ms   = dir ? ms2s : ms1s;
  const u16* vbuf = dir ? vh1 : vh2;
  float*     obuf = dir ? o2 : o1;

  // ---- phase A: wave w -> fix = fix0 + (w>>1), heads (w&1)*8 .. +7 ----
  int fsel = w >> 1;
  int fix  = fix0 + fsel;
  int hbase = (w & 1) * 8;
  bool vd[8];
#pragma unroll
  for (int i = 0; i < 8; i++) {
    int cc = i * 64 + lane;
    int mv = dir ? mask[((size_t)b * 512 + cc) * 512 + fix]
                 : mask[((size_t)b * 512 + fix) * 512 + cc];
    vd[i] = mv != 0;
  }
  bool anyl = false;
#pragma unroll
  for (int i = 0; i < 8; i++) anyl |= vd[i];
  bool useMask = (__ballot(anyl) != 0ULL);   // fully-masked row => unmask all

#pragma unroll 2
  for (int h2 = 0; h2 < 8; h2++) {
    int h = hbase + h2;
    const u16* mrow = ms + ((size_t)(b * 16 + h) * 512 + fix) * 512;
    float lg[8];
#pragma unroll
    for (int i = 0; i < 8; i++) lg[i] = b2f(mrow[i * 64 + lane]);
    float mx = -3.4e38f;
#pragma unroll
    for (int i = 0; i < 8; i++)
      if (!(useMask && !vd[i])) mx = fmaxf(mx, lg[i]);
    for (int off = 32; off; off >>= 1) mx = fmaxf(mx, __shfl_xor(mx, off));
    float s = 0.f;
#pragma unroll
    for (int i = 0; i < 8; i++) {
      float p = (useMask && !vd[i]) ? 0.f : __expf(lg[i] - mx);
      int cc = i * 64 + lane;
      pbuf[(cc * 16 + ((h + cc) & 15)) * 2 + fsel] = (_Float16)p;
      s += p;
    }
    for (int off = 32; off; off >>= 1) s += __shfl_xor(s, off);
    if (lane == 0) sden[fsel][h] = s;
  }
  __syncthreads();

  // ---- phase B: thread (w, hb=lane>>2, dq=lane&3) accumulates cc = 4*it+w ----
  int hb = lane >> 2, dq = lane & 3;
  const u16* vb = vbuf + (size_t)b * 131072 + hb * 16 + dq * 4;
  float4 acc0 = make_float4(0.f, 0.f, 0.f, 0.f);
  float4 acc1 = make_float4(0.f, 0.f, 0.f, 0.f);
  for (int it = 0; it < 128; it++) {
    int cc = it * 4 + w;
    F16x4u vv; vv.u = *(const uint2*)(vb + (size_t)cc * 256);
    F16x2u pv; pv.u = *(const u32*)&pbuf[(cc * 16 + ((hb + cc) & 15)) * 2];
    float v0 = (float)vv.h[0], v1 = (float)vv.h[1];
    float v2 = (float)vv.h[2], v3 = (float)vv.h[3];
    float p0 = (float)pv.h[0], p1 = (float)pv.h[1];
    acc0.x += p0 * v0; acc0.y += p0 * v1; acc0.z += p0 * v2; acc0.w += p0 * v3;
    acc1.x += p1 * v0; acc1.y += p1 * v1; acc1.z += p1 * v2; acc1.w += p1 * v3;
  }
#pragma unroll 1
  for (int f = 0; f < 2; f++) {
    red[w][lane] = f ? acc1 : acc0;
    __syncthreads();
    if (w == 0) {
      float4 s0 = red[0][lane], s1 = red[1][lane];
      float4 s2 = red[2][lane], s3 = red[3][lane];
      float inv = 1.f / sden[f][hb];
      float4 o;
      o.x = (s0.x + s1.x + s2.x + s3.x) * inv;
      o.y = (s0.y + s1.y + s2.y + s3.y) * inv;
      o.z = (s0.z + s1.z + s2.z + s3.z) * inv;
      o.w = (s0.w + s1.w + s2.w + s3.w) * inv;
      *(float4*)(obuf + ((size_t)b * 512 + fix0 + f) * 256 + lane * 4) = o;
    }
    __syncthreads();
  }
}

// ---------------------------------------------------------------------------
extern "C" void kernel_launch(void* const* d_in, const int* in_sizes, int n_in,
                              void* d_out, int out_size, void* d_ws, size_t ws_size,
                              hipStream_t stream) {
  const float* x1    = (const float*)d_in[0];
  const float* x2    = (const float*)d_in[1];
  const int*   attn  = (const int*)d_in[2];
  const float* cost  = (const float*)d_in[3];
  const float* Wqv1  = (const float*)d_in[4];
  const float* Wkv2  = (const float*)d_in[5];
  const float* W1    = (const float*)d_in[6];
  const float* W2    = (const float*)d_in[7];
  const float* Wout1 = (const float*)d_in[8];
  const float* Wout2 = (const float*)d_in[9];
  float* out = (float*)d_out;

  char* ws = (char*)d_ws;
  uint4* W1Bhi  = (uint4*)(ws);                              // 16 KB
  uint4* W1Blo  = (uint4*)(ws + (16 << 10));                 // 16 KB
  uint4* W2F8hi = (uint4*)(ws + (32 << 10));                 //  8 KB
  uint4* W2F8lo = (uint4*)(ws + (40 << 10));                 //  8 KB
  u16*   vh1 = (u16*)(ws + (64 << 10));                      // 512 KB [b][r][256] f16 (v1)
  u16*   vh2 = (u16*)(ws + (64 << 10) + (512 << 10));        // 512 KB [b][c][256] f16 (v2)
  u16*   ms1 = (u16*)(ws + (64 << 10) + (4 << 20));          //  16 MB [b][h][r][c]
  u16*   ms2 = (u16*)(ws + (64 << 10) + (20 << 20));         //  16 MB [b][h][c][r]
  char*  tail= (ws + (64 << 10) + (36 << 20));
  uint4* QQ4  = (uint4*)(tail);                              //   1 MB
  uint4* KH4  = (uint4*)(tail + (1 << 20));                  // 0.5 MB
  uint4* KL4z = (uint4*)(tail + (1 << 20) + (512 << 10));    //   1 MB
  float* o1  = (float*)(tail + (3 << 20));                   //   1 MB [b][r][256]
  float* o2  = (float*)(tail + (4 << 20));                   //   1 MB [b][c][256]

  gemm_mf_pack<<<dim3(32, 33), 256, 0, stream>>>(x1, Wqv1, vh1, x2, Wkv2, vh2,
                                                 W1, W2, QQ4, KH4, KL4z,
                                                 W1Bhi, W1Blo, W2F8hi, W2F8lo);

  ms_mfma6<<<dim3(32, 8, 2), 256, 0, stream>>>(QQ4, KH4, KL4z, cost,
                                               W1Bhi, W1Blo, W2F8hi, W2F8lo, ms1, ms2);

  softmax_all5b<<<dim3(256, 2, 2), 256, 0, stream>>>(ms1, ms2, attn, vh1, vh2, o1, o2);

  gemm_mf<<<dim3(16, 32), 256, 0, stream>>>(o1, Wout1, out, o2, Wout2, out + (size_t)262144, 256, 256);
}

// Round 17
// 164.405 us; speedup vs baseline: 1.1925x; 1.0447x over previous
//
#include <hip/hip_runtime.h>
#include <hip/hip_bf16.h>

typedef unsigned int   u32;
typedef unsigned short u16;

typedef __attribute__((ext_vector_type(8))) short    sh8;
typedef __attribute__((ext_vector_type(4))) float    f32x4;
typedef __attribute__((ext_vector_type(8))) _Float16 f16x8;
typedef __attribute__((ext_vector_type(2))) _Float16 f16x2;
typedef __attribute__((ext_vector_type(2))) __fp16   fp16x2raw;

union F16x8 { f16x8 v; uint4 u; f16x2 p[4]; _Float16 h[8]; };
union F16x4u { uint2 u; _Float16 h[4]; };
union F16x2u { u32 u; _Float16 h[2]; };
union CvtU  { fp16x2raw r; f16x2 p; u32 u; };

__device__ __forceinline__ float b2f(u16 u) { union { u32 i; float f; } v; v.i = ((u32)u) << 16; return v.f; }
__device__ __forceinline__ u16   f2b(float f){
  union { float f; u32 i; } v; v.f = f;
  u32 u = v.i;
  u32 r = (u + 0x7fffu + ((u >> 16) & 1u)) >> 16;   // RNE
  return (u16)r;
}
// pack two f32 -> bf16x2 (RNE), lo half = a, hi half = b
__device__ __forceinline__ u32 pk2(float a, float b) {
  __hip_bfloat162 h2 = __float22bfloat162_rn(make_float2(a, b));
  union { __hip_bfloat162 h; u32 u; } v; v.h = h2; return v.u;
}
__device__ __forceinline__ f16x2 cvtpk(float a, float b) {
  CvtU c; c.r = __builtin_amdgcn_cvt_pkrtz(a, b); return c.p;
}
__device__ __forceinline__ u32 cvtpku(float a, float b) {
  CvtU c; c.r = __builtin_amdgcn_cvt_pkrtz(a, b); return c.u;
}

__device__ __forceinline__ f32x4 mfma16(uint4 a, uint4 b, f32x4 c) {
  union { uint4 u; sh8 s; } ua, ub;
  ua.u = a; ub.u = b;
  return __builtin_amdgcn_mfma_f32_16x16x32_bf16(ua.s, ub.s, c, 0, 0, 0);
}
__device__ __forceinline__ f32x4 mfma32h(f16x8 a, f16x8 b, f32x4 c) {
  return __builtin_amdgcn_mfma_f32_16x16x32_f16(a, b, c, 0, 0, 0);
}

// split 8 consecutive f32 (one lane's K-chunk) into bf16 hi/lo operand words
__device__ __forceinline__ void split8(float4 v0, float4 v1, uint4& hi, uint4& lo) {
  float a[8] = {v0.x, v0.y, v0.z, v0.w, v1.x, v1.y, v1.z, v1.w};
  u32 hw[4], lw[4];
#pragma unroll
  for (int t = 0; t < 4; t++) {
    u32 hp = pk2(a[2 * t], a[2 * t + 1]);
    float r0 = a[2 * t]     - __uint_as_float(hp << 16);
    float r1 = a[2 * t + 1] - __uint_as_float(hp & 0xffff0000u);
    hw[t] = hp;
    lw[t] = pk2(r0, r1);
  }
  hi = make_uint4(hw[0], hw[1], hw[2], hw[3]);
  lo = make_uint4(lw[0], lw[1], lw[2], lw[3]);
}

// ---------------------------------------------------------------------------
// gemm_mf: two independent C = A @ B^T f32 GEMMs via MFMA (sel = by>>4).
// One wave per 16x16 C tile.  Used for the output projections (N=256, K=256).
// ---------------------------------------------------------------------------
__global__ void __launch_bounds__(256)
gemm_mf(const float* __restrict__ A0, const float* __restrict__ B0, float* __restrict__ C0,
        const float* __restrict__ A1, const float* __restrict__ B1, float* __restrict__ C1,
        int N, int K) {
  int t = threadIdx.x, L = t & 63, w = t >> 6;
  int cl = L & 15, q = L >> 4;
  int by = blockIdx.y, sel = by >> 4;
  const float* A  = sel ? A1 : A0;
  const float* Bw = sel ? B1 : B0;
  float*       C  = sel ? C1 : C0;
  int m0 = (by & 15) * 64 + w * 16;
  int n0 = blockIdx.x * 16;

  f32x4 acc; acc[0] = 0.f; acc[1] = 0.f; acc[2] = 0.f; acc[3] = 0.f;
  const float* ar = A  + (size_t)(m0 + cl) * K + 8 * q;
  const float* br = Bw + (size_t)(n0 + cl) * K + 8 * q;

  for (int k0 = 0; k0 < K; k0 += 32) {
    float4 av0 = *(const float4*)(ar + k0);
    float4 av1 = *(const float4*)(ar + k0 + 4);
    float4 bv0 = *(const float4*)(br + k0);
    float4 bv1 = *(const float4*)(br + k0 + 4);
    uint4 ahi, alo, bhi, blo;
    split8(av0, av1, ahi, alo);
    split8(bv0, bv1, bhi, blo);
    acc = mfma16(ahi, bhi, acc);
    acc = mfma16(ahi, blo, acc);
    acc = mfma16(alo, bhi, acc);
  }
#pragma unroll
  for (int i = 0; i < 4; i++)
    C[(size_t)(m0 + 4 * q + i) * N + n0 + cl] = acc[i];
}

// ---------------------------------------------------------------------------
// gemm_mf_pack: QKV projections (N=512, K=256) with FUSED fragment packing.
// by<32: gemm.  n0>=256 -> V stored f16 [b][row][256] (via Ld transpose).
// n0<256 (h = bx): Q/K tile transposed in per-wave LDS, emitted as frags.
// by==32, bx<8: W1 (f16x8 hi/lo A-operand) + W2 (f16x8 paired-nt) packing.
// ---------------------------------------------------------------------------
__global__ void __launch_bounds__(256)
gemm_mf_pack(const float* __restrict__ x1, const float* __restrict__ Wqv1, u16* __restrict__ vh1,
             const float* __restrict__ x2, const float* __restrict__ Wkv2, u16* __restrict__ vh2,
             const float* __restrict__ W1, const float* __restrict__ W2,
             uint4* __restrict__ QQ4, uint4* __restrict__ KH4, uint4* __restrict__ KL4z,
             uint4* __restrict__ W1F8hi, uint4* __restrict__ W1F8lo,
             uint4* __restrict__ W2F8hi, uint4* __restrict__ W2F8lo) {
  __shared__ float Ld[4][16][17];
  int t = threadIdx.x, L = t & 63, w = t >> 6;
  int cl = L & 15, q = L >> 4;
  int by = blockIdx.y;

  if (by == 32) {                       // ---- W packing blocks ----
    if (blockIdx.x >= 8) return;
    int tid = blockIdx.x * 256 + t;     // 0..2047
    if (tid < 1024) {
      // W1 A-operand f16 hi/lo: nt = tid>>6; lane L: m=j=nt*16+(L&15), k=8q+jj
      int LL = tid & 63, nt = tid >> 6;
      int j = nt * 16 + (LL & 15), qq = LL >> 4;
      F16x8 hi, lo;
#pragma unroll
      for (int jj = 0; jj < 8; jj++) {
        float wv = W1[j * 32 + qq * 8 + jj];
        hi.h[jj] = (_Float16)wv;
        lo.h[jj] = (_Float16)(wv - (float)hi.h[jj]);
      }
      W1F8hi[tid] = hi.u;
      W1F8lo[tid] = lo.u;
    } else if (tid < 1536) {
      int t2 = tid - 1024;              // p*64 + L
      int LL = t2 & 63, p = t2 >> 6;
      int h = LL & 15, qq = LL >> 4;
      F16x8 hi, lo;
#pragma unroll
      for (int jj = 0; jj < 8; jj++) {
        int j = 32 * p + ((jj >> 2) << 4) + 4 * qq + (jj & 3);
        float wv = W2[h * 256 + j];
        hi.h[jj] = (_Float16)wv;
        lo.h[jj] = (_Float16)(wv - (float)hi.h[jj]);
      }
      W2F8hi[t2] = hi.u;
      W2F8lo[t2] = lo.u;
    }
    return;
  }

  int sel = by >> 4;
  const float* A  = sel ? x2 : x1;
  const float* Bw = sel ? Wkv2 : Wqv1;
  int m0 = (by & 15) * 64 + w * 16;
  int n0 = blockIdx.x * 16;

  f32x4 acc; acc[0] = 0.f; acc[1] = 0.f; acc[2] = 0.f; acc[3] = 0.f;
  const float* ar = A  + (size_t)(m0 + cl) * 256 + 8 * q;
  const float* br = Bw + (size_t)(n0 + cl) * 256 + 8 * q;

  for (int k0 = 0; k0 < 256; k0 += 32) {
    float4 av0 = *(const float4*)(ar + k0);
    float4 av1 = *(const float4*)(ar + k0 + 4);
    float4 bv0 = *(const float4*)(br + k0);
    float4 bv1 = *(const float4*)(br + k0 + 4);
    uint4 ahi, alo, bhi, blo;
    split8(av0, av1, ahi, alo);
    split8(bv0, bv1, bhi, blo);
    acc = mfma16(ahi, bhi, acc);
    acc = mfma16(ahi, blo, acc);
    acc = mfma16(alo, bhi, acc);
  }

  int b = m0 >> 9;
  int row = (m0 & 511) + cl;            // r (or c) index after transpose

  if (n0 >= 256) {                      // ---- V half: f16 store via transpose ----
#pragma unroll
    for (int i = 0; i < 4; i++) Ld[w][cl][4 * q + i] = acc[i];
    if (q < 2) {
      float v[8];
#pragma unroll
      for (int jj = 0; jj < 8; jj++) v[jj] = Ld[w][q * 8 + jj][cl];
      uint4 o = make_uint4(cvtpku(v[0], v[1]), cvtpku(v[2], v[3]),
                           cvtpku(v[4], v[5]), cvtpku(v[6], v[7]));
      u16* vh = sel ? vh2 : vh1;
      *(uint4*)(vh + ((size_t)(b * 512) + row) * 256 + (n0 - 256) + q * 8) = o;
    }
    return;
  }

  // ---- Q/K half: per-wave 16x16 transpose, then fragment emit ----
#pragma unroll
  for (int i = 0; i < 4; i++) Ld[w][cl][4 * q + i] = acc[i];   // Ld[d][r_local]
  float v[8];
#pragma unroll
  for (int jj = 0; jj < 8; jj++) v[jj] = Ld[w][(q & 1) * 8 + jj][cl];

  int r = row;
  int h = n0 >> 4;                      // == blockIdx.x

  if (sel == 0) {                       // Q: x0.25 folded; q<2 hi, q>=2 lo
    u32 wv[4];
#pragma unroll
    for (int t2 = 0; t2 < 4; t2++) {
      float a  = v[2 * t2] * 0.25f, bb = v[2 * t2 + 1] * 0.25f;
      u32 hp = pk2(a, bb);
      if (q >= 2) {
        float r0 = a  - __uint_as_float(hp << 16);
        float r1 = bb - __uint_as_float(hp & 0xffff0000u);
        wv[t2] = pk2(r0, r1);
      } else wv[t2] = hp;
    }
    QQ4[((size_t)((b * 16 + h) * 4 + q) << 9) + r] = make_uint4(wv[0], wv[1], wv[2], wv[3]);
  } else {                              // K: hi + lo + zero slots
    u32 hw[4], lw[4];
#pragma unroll
    for (int t2 = 0; t2 < 4; t2++) {
      float a = v[2 * t2], bb = v[2 * t2 + 1];
      u32 hp = pk2(a, bb);
      float r0 = a  - __uint_as_float(hp << 16);
      float r1 = bb - __uint_as_float(hp & 0xffff0000u);
      hw[t2] = hp;
      lw[t2] = pk2(r0, r1);
    }
    if (q < 2) {
      KH4[((size_t)((b * 16 + h) * 2 + q) << 9) + r]       = make_uint4(hw[0], hw[1], hw[2], hw[3]);
      KL4z[((size_t)((b * 16 + h) * 4 + 2 + q) << 9) + r]  = make_uint4(0, 0, 0, 0);
    } else {
      KL4z[((size_t)((b * 16 + h) * 4 + (q - 2)) << 9) + r] = make_uint4(lw[0], lw[1], lw[2], lw[3]);
    }
  }
}

// ---------------------------------------------------------------------------
// ms_mfma8: f16-X redesign for occupancy.  Wave-tile = 8r x 16c; grid 1024
// blocks -> 4 waves/SIMD (launch_bounds(256,4), live state ~96 VGPR).
// Phase A: exact bf16 hi/lo QK^T (head pairs), dots stored f16-packed in a
// 17.4 KB/block LDS buffer.  X = single f16x8 fragment per r (built once,
// kept in regs).  Layer1 = 2 MFMAs (W1 f16 hi/lo as A-op), layer2 = 2 fused
// K=32 f16 MFMAs -> 6 MFMAs per (p,r), no LDS in the p-loop.
// ---------------------------------------------------------------------------
__global__ void __launch_bounds__(256, 4)
ms_mfma8(const uint4* __restrict__ QQ4, const uint4* __restrict__ KH4,
         const uint4* __restrict__ KL4z, const float* __restrict__ cost,
         const uint4* __restrict__ W1F8hi, const uint4* __restrict__ W1F8lo,
         const uint4* __restrict__ W2F8hi, const uint4* __restrict__ W2F8lo,
         u16* __restrict__ ms1, u16* __restrict__ ms2) {
  __shared__ __align__(16) u32 Dl[4 * 1088];   // per wave [8r][8h2][17] u32 (f16x2)
  int t = threadIdx.x, L = t & 63, w = t >> 6;
  int cl = L & 15, q = L >> 4;
  int b = blockIdx.z, c0 = blockIdx.x * 16;
  int r0 = blockIdx.y * 32 + w * 8;            // 8-row tile
  int off = r0 & 8;                            // which half of the 16-row MFMA we keep
  int r0a = r0 - off;                          // 16-aligned A-fragment base
  u32* D = Dl + w * 1088;

  f32x4 z; z[0] = 0.f; z[1] = 0.f; z[2] = 0.f; z[3] = 0.f;

  // ---- phase A: QK^T (bf16 hi/lo, exact), head pairs -> f16 D ----
  bool keep = (4 * q >= off) && (4 * q < off + 8);
  int rl = 4 * q - off;
#pragma unroll 2
  for (int hp = 0; hp < 8; hp++) {
    int h0 = 2 * hp, h1 = 2 * hp + 1;
    uint4 qa  = QQ4[((size_t)((b * 16 + h0) * 4 + q) << 9) + r0a + cl];
    uint4 qa2 = QQ4[((size_t)((b * 16 + h0) * 4 + (q & 1)) << 9) + r0a + cl];
    uint4 kb1 = KH4[((size_t)((b * 16 + h0) * 2 + (q & 1)) << 9) + c0 + cl];
    uint4 kb2 = KL4z[((size_t)((b * 16 + h0) * 4 + q) << 9) + c0 + cl];
    f32x4 d0 = mfma16(qa, kb1, z);
    d0 = mfma16(qa2, kb2, d0);
    uint4 qb  = QQ4[((size_t)((b * 16 + h1) * 4 + q) << 9) + r0a + cl];
    uint4 qb2 = QQ4[((size_t)((b * 16 + h1) * 4 + (q & 1)) << 9) + r0a + cl];
    uint4 kc1 = KH4[((size_t)((b * 16 + h1) * 2 + (q & 1)) << 9) + c0 + cl];
    uint4 kc2 = KL4z[((size_t)((b * 16 + h1) * 4 + q) << 9) + c0 + cl];
    f32x4 d1 = mfma16(qb, kc1, z);
    d1 = mfma16(qb2, kc2, d1);
    if (keep) {
#pragma unroll
      for (int i = 0; i < 4; i++)
        D[(rl + i) * 136 + hp * 17 + cl] = cvtpku(d0[i], d1[i]);
    }
  }

  // ---- phase A2: build X f16x8 fragments (once), kept in registers ----
  F16x8 xv[8];
#pragma unroll
  for (int rr = 0; rr < 8; rr++) {
    float cv = cost[((size_t)(b * 512) + r0 + rr) * 512 + c0 + cl];
    u32 ch = cvtpku(0.f, cv);                  // cost f16 in high half
    u32 ua = D[rr * 136 + (2 * q) * 17 + cl];
    u32 ub = D[rr * 136 + (2 * q + 1) * 17 + cl];
    xv[rr].u = make_uint4((ua & 0xffffu) | ch, (ua >> 16) | ch,
                          (ub & 0xffffu) | ch, (ub >> 16) | ch);
  }

  // ---- phase B: p-outer MLP, 6 MFMAs per (p,r), zero LDS ----
  f32x4 acc2[8];
#pragma unroll
  for (int rr = 0; rr < 8; rr++) acc2[rr] = z;

#pragma unroll 1
  for (int p = 0; p < 8; p++) {
    F16x8 w1h0, w1l0, w1h1, w1l1, w2h, w2l;
    w1h0.u = W1F8hi[(2 * p) * 64 + L];
    w1l0.u = W1F8lo[(2 * p) * 64 + L];
    w1h1.u = W1F8hi[(2 * p + 1) * 64 + L];
    w1l1.u = W1F8lo[(2 * p + 1) * 64 + L];
    w2h.u  = W2F8hi[p * 64 + L];
    w2l.u  = W2F8lo[p * 64 + L];
#pragma unroll
    for (int rr = 0; rr < 8; rr++) {
      f32x4 a0 = mfma32h(w1h0.v, xv[rr].v, z);
      a0 = mfma32h(w1l0.v, xv[rr].v, a0);
      f32x4 a1 = mfma32h(w1h1.v, xv[rr].v, z);
      a1 = mfma32h(w1l1.v, xv[rr].v, a1);
      F16x8 hf;
      hf.p[0] = cvtpk(fmaxf(a0[0], 0.f), fmaxf(a0[1], 0.f));
      hf.p[1] = cvtpk(fmaxf(a0[2], 0.f), fmaxf(a0[3], 0.f));
      hf.p[2] = cvtpk(fmaxf(a1[0], 0.f), fmaxf(a1[1], 0.f));
      hf.p[3] = cvtpk(fmaxf(a1[2], 0.f), fmaxf(a1[3], 0.f));
      acc2[rr] = mfma32h(hf.v, w2h.v, acc2[rr]);
      acc2[rr] = mfma32h(hf.v, w2l.v, acc2[rr]);
    }
  }

  // ---- epilogue: lane (q,cl) holds MS[h=cl][c=c0+4q+i][r0..r0+7] ----
  u32* ms1u = (u32*)ms1;
#pragma unroll
  for (int rr = 0; rr < 8; rr++) {
    size_t base = ((size_t)(b * 16 + cl) * 512 + (r0 + rr)) * 256 + (c0 >> 1) + q * 2;
    ms1u[base]     = pk2(acc2[rr][0], acc2[rr][1]);
    ms1u[base + 1] = pk2(acc2[rr][2], acc2[rr][3]);
  }
  u32* ms2u = (u32*)ms2;
#pragma unroll
  for (int i = 0; i < 4; i++) {
    int c = c0 + 4 * q + i;
    u32 o[4];
#pragma unroll
    for (int j = 0; j < 4; j++)
      o[j] = pk2(acc2[2 * j][i], acc2[2 * j + 1][i]);
    size_t base2 = ((size_t)(b * 16 + cl) * 512 + c) * 256 + (r0 >> 1);
    *(uint4*)&ms2u[base2] = make_uint4(o[0], o[1], o[2], o[3]);
  }
}

// ---------------------------------------------------------------------------
// softmax_all5b: 2 fixes per block (R16 champion, verbatim).
// ---------------------------------------------------------------------------
__global__ void __launch_bounds__(256)
softmax_all5b(const u16* __restrict__ ms1s, const u16* __restrict__ ms2s,
              const int* __restrict__ mask,
              const u16* __restrict__ vh1, const u16* __restrict__ vh2,
              float* __restrict__ o1, float* __restrict__ o2) {
  __shared__ _Float16 pbuf[512 * 16 * 2];   // 32 KB
  __shared__ float    sden[2][16];
  __shared__ float4   red[4][64];
  int t = threadIdx.x, lane = t & 63, w = t >> 6;
  int fix0 = blockIdx.x * 2, b = blockIdx.y, dir = blockIdx.z;
  const u16* ms   = dir ? ms2s : ms1s;
  const u16* vbuf = dir ? vh1 : vh2;
  float*     obuf = dir ? o2 : o1;

  int fsel = w >> 1;
  int fix  = fix0 + fsel;
  int hbase = (w & 1) * 8;
  bool vd[8];
#pragma unroll
  for (int i = 0; i < 8; i++) {
    int cc = i * 64 + lane;
    int mv = dir ? mask[((size_t)b * 512 + cc) * 512 + fix]
                 : mask[((size_t)b * 512 + fix) * 512 + cc];
    vd[i] = mv != 0;
  }
  bool anyl = false;
#pragma unroll
  for (int i = 0; i < 8; i++) anyl |= vd[i];
  bool useMask = (__ballot(anyl) != 0ULL);   // fully-masked row => unmask all

#pragma unroll 2
  for (int h2 = 0; h2 < 8; h2++) {
    int h = hbase + h2;
    const u16* mrow = ms + ((size_t)(b * 16 + h) * 512 + fix) * 512;
    float lg[8];
#pragma unroll
    for (int i = 0; i < 8; i++) lg[i] = b2f(mrow[i * 64 + lane]);
    float mx = -3.4e38f;
#pragma unroll
    for (int i = 0; i < 8; i++)
      if (!(useMask && !vd[i])) mx = fmaxf(mx, lg[i]);
    for (int off = 32; off; off >>= 1) mx = fmaxf(mx, __shfl_xor(mx, off));
    float s = 0.f;
#pragma unroll
    for (int i = 0; i < 8; i++) {
      float p = (useMask && !vd[i]) ? 0.f : __expf(lg[i] - mx);
      int cc = i * 64 + lane;
      pbuf[(cc * 16 + ((h + cc) & 15)) * 2 + fsel] = (_Float16)p;
      s += p;
    }
    for (int off = 32; off; off >>= 1) s += __shfl_xor(s, off);
    if (lane == 0) sden[fsel][h] = s;
  }
  __syncthreads();

  int hb = lane >> 2, dq = lane & 3;
  const u16* vb = vbuf + (size_t)b * 131072 + hb * 16 + dq * 4;
  float4 acc0 = make_float4(0.f, 0.f, 0.f, 0.f);
  float4 acc1 = make_float4(0.f, 0.f, 0.f, 0.f);
  for (int it = 0; it < 128; it++) {
    int cc = it * 4 + w;
    F16x4u vv; vv.u = *(const uint2*)(vb + (size_t)cc * 256);
    F16x2u pv; pv.u = *(const u32*)&pbuf[(cc * 16 + ((hb + cc) & 15)) * 2];
    float v0 = (float)vv.h[0], v1 = (float)vv.h[1];
    float v2 = (float)vv.h[2], v3 = (float)vv.h[3];
    float p0 = (float)pv.h[0], p1 = (float)pv.h[1];
    acc0.x += p0 * v0; acc0.y += p0 * v1; acc0.z += p0 * v2; acc0.w += p0 * v3;
    acc1.x += p1 * v0; acc1.y += p1 * v1; acc1.z += p1 * v2; acc1.w += p1 * v3;
  }
#pragma unroll 1
  for (int f = 0; f < 2; f++) {
    red[w][lane] = f ? acc1 : acc0;
    __syncthreads();
    if (w == 0) {
      float4 s0 = red[0][lane], s1 = red[1][lane];
      float4 s2 = red[2][lane], s3 = red[3][lane];
      float inv = 1.f / sden[f][hb];
      float4 o;
      o.x = (s0.x + s1.x + s2.x + s3.x) * inv;
      o.y = (s0.y + s1.y + s2.y + s3.y) * inv;
      o.z = (s0.z + s1.z + s2.z + s3.z) * inv;
      o.w = (s0.w + s1.w + s2.w + s3.w) * inv;
      *(float4*)(obuf + ((size_t)b * 512 + fix0 + f) * 256 + lane * 4) = o;
    }
    __syncthreads();
  }
}

// ---------------------------------------------------------------------------
extern "C" void kernel_launch(void* const* d_in, const int* in_sizes, int n_in,
                              void* d_out, int out_size, void* d_ws, size_t ws_size,
                              hipStream_t stream) {
  const float* x1    = (const float*)d_in[0];
  const float* x2    = (const float*)d_in[1];
  const int*   attn  = (const int*)d_in[2];
  const float* cost  = (const float*)d_in[3];
  const float* Wqv1  = (const float*)d_in[4];
  const float* Wkv2  = (const float*)d_in[5];
  const float* W1    = (const float*)d_in[6];
  const float* W2    = (const float*)d_in[7];
  const float* Wout1 = (const float*)d_in[8];
  const float* Wout2 = (const float*)d_in[9];
  float* out = (float*)d_out;

  char* ws = (char*)d_ws;
  uint4* W1F8hi = (uint4*)(ws);                              // 16 KB
  uint4* W1F8lo = (uint4*)(ws + (16 << 10));                 // 16 KB
  uint4* W2F8hi = (uint4*)(ws + (32 << 10));                 //  8 KB
  uint4* W2F8lo = (uint4*)(ws + (40 << 10));                 //  8 KB
  u16*   vh1 = (u16*)(ws + (64 << 10));                      // 512 KB [b][r][256] f16 (v1)
  u16*   vh2 = (u16*)(ws + (64 << 10) + (512 << 10));        // 512 KB [b][c][256] f16 (v2)
  u16*   ms1 = (u16*)(ws + (64 << 10) + (4 << 20));          //  16 MB [b][h][r][c]
  u16*   ms2 = (u16*)(ws + (64 << 10) + (20 << 20));         //  16 MB [b][h][c][r]
  char*  tail= (ws + (64 << 10) + (36 << 20));
  uint4* QQ4  = (uint4*)(tail);                              //   1 MB
  uint4* KH4  = (uint4*)(tail + (1 << 20));                  // 0.5 MB
  uint4* KL4z = (uint4*)(tail + (1 << 20) + (512 << 10));    //   1 MB
  float* o1  = (float*)(tail + (3 << 20));                   //   1 MB [b][r][256]
  float* o2  = (float*)(tail + (4 << 20));                   //   1 MB [b][c][256]

  gemm_mf_pack<<<dim3(32, 33), 256, 0, stream>>>(x1, Wqv1, vh1, x2, Wkv2, vh2,
                                                 W1, W2, QQ4, KH4, KL4z,
                                                 W1F8hi, W1F8lo, W2F8hi, W2F8lo);

  ms_mfma8<<<dim3(32, 16, 2), 256, 0, stream>>>(QQ4, KH4, KL4z, cost,
                                                W1F8hi, W1F8lo, W2F8hi, W2F8lo, ms1, ms2);

  softmax_all5b<<<dim3(256, 2, 2), 256, 0, stream>>>(ms1, ms2, attn, vh1, vh2, o1, o2);

  gemm_mf<<<dim3(16, 32), 256, 0, stream>>>(o1, Wout1, out, o2, Wout2, out + (size_t)262144, 256, 256);
}

// Round 18
// 159.324 us; speedup vs baseline: 1.2305x; 1.0319x over previous
//
#include <hip/hip_runtime.h>
#include <hip/hip_bf16.h>

typedef unsigned int   u32;
typedef unsigned short u16;

typedef __attribute__((ext_vector_type(8))) short    sh8;
typedef __attribute__((ext_vector_type(4))) float    f32x4;
typedef __attribute__((ext_vector_type(8))) _Float16 f16x8;
typedef __attribute__((ext_vector_type(2))) _Float16 f16x2;
typedef __attribute__((ext_vector_type(2))) __fp16   fp16x2raw;

union F16x8 { f16x8 v; uint4 u; f16x2 p[4]; _Float16 h[8]; };
union F16x4u { uint2 u; _Float16 h[4]; };
union F16x2u { u32 u; _Float16 h[2]; };
union CvtU  { fp16x2raw r; f16x2 p; u32 u; };

__device__ __forceinline__ float b2f(u16 u) { union { u32 i; float f; } v; v.i = ((u32)u) << 16; return v.f; }
__device__ __forceinline__ u16   f2b(float f){
  union { float f; u32 i; } v; v.f = f;
  u32 u = v.i;
  u32 r = (u + 0x7fffu + ((u >> 16) & 1u)) >> 16;   // RNE
  return (u16)r;
}
// pack two f32 -> bf16x2 (RNE), lo half = a, hi half = b
__device__ __forceinline__ u32 pk2(float a, float b) {
  __hip_bfloat162 h2 = __float22bfloat162_rn(make_float2(a, b));
  union { __hip_bfloat162 h; u32 u; } v; v.h = h2; return v.u;
}
__device__ __forceinline__ f16x2 cvtpk(float a, float b) {
  CvtU c; c.r = __builtin_amdgcn_cvt_pkrtz(a, b); return c.p;
}
__device__ __forceinline__ u32 cvtpku(float a, float b) {
  CvtU c; c.r = __builtin_amdgcn_cvt_pkrtz(a, b); return c.u;
}

__device__ __forceinline__ f32x4 mfma16(uint4 a, uint4 b, f32x4 c) {
  union { uint4 u; sh8 s; } ua, ub;
  ua.u = a; ub.u = b;
  return __builtin_amdgcn_mfma_f32_16x16x32_bf16(ua.s, ub.s, c, 0, 0, 0);
}
__device__ __forceinline__ f32x4 mfma32h(f16x8 a, f16x8 b, f32x4 c) {
  return __builtin_amdgcn_mfma_f32_16x16x32_f16(a, b, c, 0, 0, 0);
}

// split 8 consecutive f32 (one lane's K-chunk) into bf16 hi/lo operand words
__device__ __forceinline__ void split8(float4 v0, float4 v1, uint4& hi, uint4& lo) {
  float a[8] = {v0.x, v0.y, v0.z, v0.w, v1.x, v1.y, v1.z, v1.w};
  u32 hw[4], lw[4];
#pragma unroll
  for (int t = 0; t < 4; t++) {
    u32 hp = pk2(a[2 * t], a[2 * t + 1]);
    float r0 = a[2 * t]     - __uint_as_float(hp << 16);
    float r1 = a[2 * t + 1] - __uint_as_float(hp & 0xffff0000u);
    hw[t] = hp;
    lw[t] = pk2(r0, r1);
  }
  hi = make_uint4(hw[0], hw[1], hw[2], hw[3]);
  lo = make_uint4(lw[0], lw[1], lw[2], lw[3]);
}

// ---------------------------------------------------------------------------
// gemm_mf: two independent C = A @ B^T f32 GEMMs via MFMA (sel = by>>4).
// One wave per 16x16 C tile.  Used for the output projections (N=256, K=256).
// ---------------------------------------------------------------------------
__global__ void __launch_bounds__(256)
gemm_mf(const float* __restrict__ A0, const float* __restrict__ B0, float* __restrict__ C0,
        const float* __restrict__ A1, const float* __restrict__ B1, float* __restrict__ C1,
        int N, int K) {
  int t = threadIdx.x, L = t & 63, w = t >> 6;
  int cl = L & 15, q = L >> 4;
  int by = blockIdx.y, sel = by >> 4;
  const float* A  = sel ? A1 : A0;
  const float* Bw = sel ? B1 : B0;
  float*       C  = sel ? C1 : C0;
  int m0 = (by & 15) * 64 + w * 16;
  int n0 = blockIdx.x * 16;

  f32x4 acc; acc[0] = 0.f; acc[1] = 0.f; acc[2] = 0.f; acc[3] = 0.f;
  const float* ar = A  + (size_t)(m0 + cl) * K + 8 * q;
  const float* br = Bw + (size_t)(n0 + cl) * K + 8 * q;

  for (int k0 = 0; k0 < K; k0 += 32) {
    float4 av0 = *(const float4*)(ar + k0);
    float4 av1 = *(const float4*)(ar + k0 + 4);
    float4 bv0 = *(const float4*)(br + k0);
    float4 bv1 = *(const float4*)(br + k0 + 4);
    uint4 ahi, alo, bhi, blo;
    split8(av0, av1, ahi, alo);
    split8(bv0, bv1, bhi, blo);
    acc = mfma16(ahi, bhi, acc);
    acc = mfma16(ahi, blo, acc);
    acc = mfma16(alo, bhi, acc);
  }
#pragma unroll
  for (int i = 0; i < 4; i++)
    C[(size_t)(m0 + 4 * q + i) * N + n0 + cl] = acc[i];
}

// ---------------------------------------------------------------------------
// gemm_mf_pack: QKV projections (N=512, K=256) with FUSED fragment packing.
// by<32: gemm.  n0>=256 -> V stored f16 [b][row][256] (via Ld transpose).
// n0<256 (h = bx): Q/K tile transposed in per-wave LDS, emitted as frags.
// by==32, bx<8: W1 (f16x8 hi/lo A-operand) + W2 (f16x8 paired-nt) packing.
// ---------------------------------------------------------------------------
__global__ void __launch_bounds__(256)
gemm_mf_pack(const float* __restrict__ x1, const float* __restrict__ Wqv1, u16* __restrict__ vh1,
             const float* __restrict__ x2, const float* __restrict__ Wkv2, u16* __restrict__ vh2,
             const float* __restrict__ W1, const float* __restrict__ W2,
             uint4* __restrict__ QQ4, uint4* __restrict__ KH4, uint4* __restrict__ KL4z,
             uint4* __restrict__ W1F8hi, uint4* __restrict__ W1F8lo,
             uint4* __restrict__ W2F8hi, uint4* __restrict__ W2F8lo) {
  __shared__ float Ld[4][16][17];
  int t = threadIdx.x, L = t & 63, w = t >> 6;
  int cl = L & 15, q = L >> 4;
  int by = blockIdx.y;

  if (by == 32) {                       // ---- W packing blocks ----
    if (blockIdx.x >= 8) return;
    int tid = blockIdx.x * 256 + t;     // 0..2047
    if (tid < 1024) {
      // W1 A-operand f16 hi/lo: nt = tid>>6; lane L: m=j=nt*16+(L&15), k=8q+jj
      int LL = tid & 63, nt = tid >> 6;
      int j = nt * 16 + (LL & 15), qq = LL >> 4;
      F16x8 hi, lo;
#pragma unroll
      for (int jj = 0; jj < 8; jj++) {
        float wv = W1[j * 32 + qq * 8 + jj];
        hi.h[jj] = (_Float16)wv;
        lo.h[jj] = (_Float16)(wv - (float)hi.h[jj]);
      }
      W1F8hi[tid] = hi.u;
      W1F8lo[tid] = lo.u;
    } else if (tid < 1536) {
      int t2 = tid - 1024;              // p*64 + L
      int LL = t2 & 63, p = t2 >> 6;
      int h = LL & 15, qq = LL >> 4;
      F16x8 hi, lo;
#pragma unroll
      for (int jj = 0; jj < 8; jj++) {
        int j = 32 * p + ((jj >> 2) << 4) + 4 * qq + (jj & 3);
        float wv = W2[h * 256 + j];
        hi.h[jj] = (_Float16)wv;
        lo.h[jj] = (_Float16)(wv - (float)hi.h[jj]);
      }
      W2F8hi[t2] = hi.u;
      W2F8lo[t2] = lo.u;
    }
    return;
  }

  int sel = by >> 4;
  const float* A  = sel ? x2 : x1;
  const float* Bw = sel ? Wkv2 : Wqv1;
  int m0 = (by & 15) * 64 + w * 16;
  int n0 = blockIdx.x * 16;

  f32x4 acc; acc[0] = 0.f; acc[1] = 0.f; acc[2] = 0.f; acc[3] = 0.f;
  const float* ar = A  + (size_t)(m0 + cl) * 256 + 8 * q;
  const float* br = Bw + (size_t)(n0 + cl) * 256 + 8 * q;

  for (int k0 = 0; k0 < 256; k0 += 32) {
    float4 av0 = *(const float4*)(ar + k0);
    float4 av1 = *(const float4*)(ar + k0 + 4);
    float4 bv0 = *(const float4*)(br + k0);
    float4 bv1 = *(const float4*)(br + k0 + 4);
    uint4 ahi, alo, bhi, blo;
    split8(av0, av1, ahi, alo);
    split8(bv0, bv1, bhi, blo);
    acc = mfma16(ahi, bhi, acc);
    acc = mfma16(ahi, blo, acc);
    acc = mfma16(alo, bhi, acc);
  }

  int b = m0 >> 9;
  int row = (m0 & 511) + cl;            // r (or c) index after transpose

  if (n0 >= 256) {                      // ---- V half: f16 store via transpose ----
#pragma unroll
    for (int i = 0; i < 4; i++) Ld[w][cl][4 * q + i] = acc[i];
    if (q < 2) {
      float v[8];
#pragma unroll
      for (int jj = 0; jj < 8; jj++) v[jj] = Ld[w][q * 8 + jj][cl];
      uint4 o = make_uint4(cvtpku(v[0], v[1]), cvtpku(v[2], v[3]),
                           cvtpku(v[4], v[5]), cvtpku(v[6], v[7]));
      u16* vh = sel ? vh2 : vh1;
      *(uint4*)(vh + ((size_t)(b * 512) + row) * 256 + (n0 - 256) + q * 8) = o;
    }
    return;
  }

  // ---- Q/K half: per-wave 16x16 transpose, then fragment emit ----
#pragma unroll
  for (int i = 0; i < 4; i++) Ld[w][cl][4 * q + i] = acc[i];   // Ld[d][r_local]
  float v[8];
#pragma unroll
  for (int jj = 0; jj < 8; jj++) v[jj] = Ld[w][(q & 1) * 8 + jj][cl];

  int r = row;
  int h = n0 >> 4;                      // == blockIdx.x

  if (sel == 0) {                       // Q: x0.25 folded; q<2 hi, q>=2 lo
    u32 wv[4];
#pragma unroll
    for (int t2 = 0; t2 < 4; t2++) {
      float a  = v[2 * t2] * 0.25f, bb = v[2 * t2 + 1] * 0.25f;
      u32 hp = pk2(a, bb);
      if (q >= 2) {
        float r0 = a  - __uint_as_float(hp << 16);
        float r1 = bb - __uint_as_float(hp & 0xffff0000u);
        wv[t2] = pk2(r0, r1);
      } else wv[t2] = hp;
    }
    QQ4[((size_t)((b * 16 + h) * 4 + q) << 9) + r] = make_uint4(wv[0], wv[1], wv[2], wv[3]);
  } else {                              // K: hi + lo + zero slots
    u32 hw[4], lw[4];
#pragma unroll
    for (int t2 = 0; t2 < 4; t2++) {
      float a = v[2 * t2], bb = v[2 * t2 + 1];
      u32 hp = pk2(a, bb);
      float r0 = a  - __uint_as_float(hp << 16);
      float r1 = bb - __uint_as_float(hp & 0xffff0000u);
      hw[t2] = hp;
      lw[t2] = pk2(r0, r1);
    }
    if (q < 2) {
      KH4[((size_t)((b * 16 + h) * 2 + q) << 9) + r]       = make_uint4(hw[0], hw[1], hw[2], hw[3]);
      KL4z[((size_t)((b * 16 + h) * 4 + 2 + q) << 9) + r]  = make_uint4(0, 0, 0, 0);
    } else {
      KL4z[((size_t)((b * 16 + h) * 4 + (q - 2)) << 9) + r] = make_uint4(lw[0], lw[1], lw[2], lw[3]);
    }
  }
}

// ---------------------------------------------------------------------------
// ms_mfma8b: like ms_mfma8 but phase A is DEDUPLICATED across wave pairs:
// R17's waves w, w^1 shared the same 16-aligned r-tile and computed identical
// QK MFMAs, discarding opposite halves.  Now wave (w&1)==0 computes head
// pairs 0..3, (w&1)==1 computes 4..7, into a shared per-pair D tile; one
// __syncthreads; each wave consumes its 8 rows.  Phase A MFMAs and fragment
// loads halve.  Phase B unchanged (6 MFMAs per (p,r), X in registers).
// ---------------------------------------------------------------------------
__global__ void __launch_bounds__(256, 4)
ms_mfma8b(const uint4* __restrict__ QQ4, const uint4* __restrict__ KH4,
          const uint4* __restrict__ KL4z, const float* __restrict__ cost,
          const uint4* __restrict__ W1F8hi, const uint4* __restrict__ W1F8lo,
          const uint4* __restrict__ W2F8hi, const uint4* __restrict__ W2F8lo,
          u16* __restrict__ ms1, u16* __restrict__ ms2) {
  __shared__ __align__(16) u32 Dl[2 * 2176];   // per wave-pair [16r][8hp][17]
  int t = threadIdx.x, L = t & 63, w = t >> 6;
  int cl = L & 15, q = L >> 4;
  int b = blockIdx.z, c0 = blockIdx.x * 16;
  int pairId = w >> 1, wl = w & 1;
  int r0a = blockIdx.y * 32 + pairId * 16;     // 16-aligned shared tile base
  int r0  = r0a + wl * 8;                      // this wave's 8 output rows
  u32* D = Dl + pairId * 2176;

  f32x4 z; z[0] = 0.f; z[1] = 0.f; z[2] = 0.f; z[3] = 0.f;

  // ---- phase A: 4 head-pairs per wave (hp = wl*4 + i), full 16-row tile ----
#pragma unroll 2
  for (int hpi = 0; hpi < 4; hpi++) {
    int hp = wl * 4 + hpi;
    int h0 = 2 * hp, h1 = 2 * hp + 1;
    uint4 qa  = QQ4[((size_t)((b * 16 + h0) * 4 + q) << 9) + r0a + cl];
    uint4 qa2 = QQ4[((size_t)((b * 16 + h0) * 4 + (q & 1)) << 9) + r0a + cl];
    uint4 kb1 = KH4[((size_t)((b * 16 + h0) * 2 + (q & 1)) << 9) + c0 + cl];
    uint4 kb2 = KL4z[((size_t)((b * 16 + h0) * 4 + q) << 9) + c0 + cl];
    f32x4 d0 = mfma16(qa, kb1, z);
    d0 = mfma16(qa2, kb2, d0);
    uint4 qb  = QQ4[((size_t)((b * 16 + h1) * 4 + q) << 9) + r0a + cl];
    uint4 qb2 = QQ4[((size_t)((b * 16 + h1) * 4 + (q & 1)) << 9) + r0a + cl];
    uint4 kc1 = KH4[((size_t)((b * 16 + h1) * 2 + (q & 1)) << 9) + c0 + cl];
    uint4 kc2 = KL4z[((size_t)((b * 16 + h1) * 4 + q) << 9) + c0 + cl];
    f32x4 d1 = mfma16(qb, kc1, z);
    d1 = mfma16(qb2, kc2, d1);
#pragma unroll
    for (int i = 0; i < 4; i++)
      D[(4 * q + i) * 136 + hp * 17 + cl] = cvtpku(d0[i], d1[i]);
  }
  __syncthreads();

  // ---- phase A2: build X f16x8 fragments (once), kept in registers ----
  F16x8 xv[8];
#pragma unroll
  for (int rr = 0; rr < 8; rr++) {
    int rl = wl * 8 + rr;
    float cv = cost[((size_t)(b * 512) + r0 + rr) * 512 + c0 + cl];
    u32 ch = cvtpku(0.f, cv);                  // cost f16 in high half
    u32 ua = D[rl * 136 + (2 * q) * 17 + cl];
    u32 ub = D[rl * 136 + (2 * q + 1) * 17 + cl];
    xv[rr].u = make_uint4((ua & 0xffffu) | ch, (ua >> 16) | ch,
                          (ub & 0xffffu) | ch, (ub >> 16) | ch);
  }

  // ---- phase B: p-outer MLP, 6 MFMAs per (p,r), zero LDS ----
  f32x4 acc2[8];
#pragma unroll
  for (int rr = 0; rr < 8; rr++) acc2[rr] = z;

#pragma unroll 1
  for (int p = 0; p < 8; p++) {
    F16x8 w1h0, w1l0, w1h1, w1l1, w2h, w2l;
    w1h0.u = W1F8hi[(2 * p) * 64 + L];
    w1l0.u = W1F8lo[(2 * p) * 64 + L];
    w1h1.u = W1F8hi[(2 * p + 1) * 64 + L];
    w1l1.u = W1F8lo[(2 * p + 1) * 64 + L];
    w2h.u  = W2F8hi[p * 64 + L];
    w2l.u  = W2F8lo[p * 64 + L];
#pragma unroll
    for (int rr = 0; rr < 8; rr++) {
      f32x4 a0 = mfma32h(w1h0.v, xv[rr].v, z);
      a0 = mfma32h(w1l0.v, xv[rr].v, a0);
      f32x4 a1 = mfma32h(w1h1.v, xv[rr].v, z);
      a1 = mfma32h(w1l1.v, xv[rr].v, a1);
      F16x8 hf;
      hf.p[0] = cvtpk(fmaxf(a0[0], 0.f), fmaxf(a0[1], 0.f));
      hf.p[1] = cvtpk(fmaxf(a0[2], 0.f), fmaxf(a0[3], 0.f));
      hf.p[2] = cvtpk(fmaxf(a1[0], 0.f), fmaxf(a1[1], 0.f));
      hf.p[3] = cvtpk(fmaxf(a1[2], 0.f), fmaxf(a1[3], 0.f));
      acc2[rr] = mfma32h(hf.v, w2h.v, acc2[rr]);
      acc2[rr] = mfma32h(hf.v, w2l.v, acc2[rr]);
    }
  }

  // ---- epilogue: lane (q,cl) holds MS[h=cl][c=c0+4q+i][r0..r0+7] ----
  u32* ms1u = (u32*)ms1;
#pragma unroll
  for (int rr = 0; rr < 8; rr++) {
    size_t base = ((size_t)(b * 16 + cl) * 512 + (r0 + rr)) * 256 + (c0 >> 1) + q * 2;
    ms1u[base]     = pk2(acc2[rr][0], acc2[rr][1]);
    ms1u[base + 1] = pk2(acc2[rr][2], acc2[rr][3]);
  }
  u32* ms2u = (u32*)ms2;
#pragma unroll
  for (int i = 0; i < 4; i++) {
    int c = c0 + 4 * q + i;
    u32 o[4];
#pragma unroll
    for (int j = 0; j < 4; j++)
      o[j] = pk2(acc2[2 * j][i], acc2[2 * j + 1][i]);
    size_t base2 = ((size_t)(b * 16 + cl) * 512 + c) * 256 + (r0 >> 1);
    *(uint4*)&ms2u[base2] = make_uint4(o[0], o[1], o[2], o[3]);
  }
}

// ---------------------------------------------------------------------------
// softmax_all5b: 2 fixes per block (R16 champion, verbatim).
// ---------------------------------------------------------------------------
__global__ void __launch_bounds__(256)
softmax_all5b(const u16* __restrict__ ms1s, const u16* __restrict__ ms2s,
              const int* __restrict__ mask,
              const u16* __restrict__ vh1, const u16* __restrict__ vh2,
              float* __restrict__ o1, float* __restrict__ o2) {
  __shared__ _Float16 pbuf[512 * 16 * 2];   // 32 KB
  __shared__ float    sden[2][16];
  __shared__ float4   red[4][64];
  int t = threadIdx.x, lane = t & 63, w = t >> 6;
  int fix0 = blockIdx.x * 2, b = blockIdx.y, dir = blockIdx.z;
  const u16* ms   = dir ? ms2s : ms1s;
  const u16* vbuf = dir ? vh1 : vh2;
  float*     obuf = dir ? o2 : o1;

  int fsel = w >> 1;
  int fix  = fix0 + fsel;
  int hbase = (w & 1) * 8;
  bool vd[8];
#pragma unroll
  for (int i = 0; i < 8; i++) {
    int cc = i * 64 + lane;
    int mv = dir ? mask[((size_t)b * 512 + cc) * 512 + fix]
                 : mask[((size_t)b * 512 + fix) * 512 + cc];
    vd[i] = mv != 0;
  }
  bool anyl = false;
#pragma unroll
  for (int i = 0; i < 8; i++) anyl |= vd[i];
  bool useMask = (__ballot(anyl) != 0ULL);   // fully-masked row => unmask all

#pragma unroll 2
  for (int h2 = 0; h2 < 8; h2++) {
    int h = hbase + h2;
    const u16* mrow = ms + ((size_t)(b * 16 + h) * 512 + fix) * 512;
    float lg[8];
#pragma unroll
    for (int i = 0; i < 8; i++) lg[i] = b2f(mrow[i * 64 + lane]);
    float mx = -3.4e38f;
#pragma unroll
    for (int i = 0; i < 8; i++)
      if (!(useMask && !vd[i])) mx = fmaxf(mx, lg[i]);
    for (int off = 32; off; off >>= 1) mx = fmaxf(mx, __shfl_xor(mx, off));
    float s = 0.f;
#pragma unroll
    for (int i = 0; i < 8; i++) {
      float p = (useMask && !vd[i]) ? 0.f : __expf(lg[i] - mx);
      int cc = i * 64 + lane;
      pbuf[(cc * 16 + ((h + cc) & 15)) * 2 + fsel] = (_Float16)p;
      s += p;
    }
    for (int off = 32; off; off >>= 1) s += __shfl_xor(s, off);
    if (lane == 0) sden[fsel][h] = s;
  }
  __syncthreads();

  int hb = lane >> 2, dq = lane & 3;
  const u16* vb = vbuf + (size_t)b * 131072 + hb * 16 + dq * 4;
  float4 acc0 = make_float4(0.f, 0.f, 0.f, 0.f);
  float4 acc1 = make_float4(0.f, 0.f, 0.f, 0.f);
  for (int it = 0; it < 128; it++) {
    int cc = it * 4 + w;
    F16x4u vv; vv.u = *(const uint2*)(vb + (size_t)cc * 256);
    F16x2u pv; pv.u = *(const u32*)&pbuf[(cc * 16 + ((hb + cc) & 15)) * 2];
    float v0 = (float)vv.h[0], v1 = (float)vv.h[1];
    float v2 = (float)vv.h[2], v3 = (float)vv.h[3];
    float p0 = (float)pv.h[0], p1 = (float)pv.h[1];
    acc0.x += p0 * v0; acc0.y += p0 * v1; acc0.z += p0 * v2; acc0.w += p0 * v3;
    acc1.x += p1 * v0; acc1.y += p1 * v1; acc1.z += p1 * v2; acc1.w += p1 * v3;
  }
#pragma unroll 1
  for (int f = 0; f < 2; f++) {
    red[w][lane] = f ? acc1 : acc0;
    __syncthreads();
    if (w == 0) {
      float4 s0 = red[0][lane], s1 = red[1][lane];
      float4 s2 = red[2][lane], s3 = red[3][lane];
      float inv = 1.f / sden[f][hb];
      float4 o;
      o.x = (s0.x + s1.x + s2.x + s3.x) * inv;
      o.y = (s0.y + s1.y + s2.y + s3.y) * inv;
      o.z = (s0.z + s1.z + s2.z + s3.z) * inv;
      o.w = (s0.w + s1.w + s2.w + s3.w) * inv;
      *(float4*)(obuf + ((size_t)b * 512 + fix0 + f) * 256 + lane * 4) = o;
    }
    __syncthreads();
  }
}

// ---------------------------------------------------------------------------
extern "C" void kernel_launch(void* const* d_in, const int* in_sizes, int n_in,
                              void* d_out, int out_size, void* d_ws, size_t ws_size,
                              hipStream_t stream) {
  const float* x1    = (const float*)d_in[0];
  const float* x2    = (const float*)d_in[1];
  const int*   attn  = (const int*)d_in[2];
  const float* cost  = (const float*)d_in[3];
  const float* Wqv1  = (const float*)d_in[4];
  const float* Wkv2  = (const float*)d_in[5];
  const float* W1    = (const float*)d_in[6];
  const float* W2    = (const float*)d_in[7];
  const float* Wout1 = (const float*)d_in[8];
  const float* Wout2 = (const float*)d_in[9];
  float* out = (float*)d_out;

  char* ws = (char*)d_ws;
  uint4* W1F8hi = (uint4*)(ws);                              // 16 KB
  uint4* W1F8lo = (uint4*)(ws + (16 << 10));                 // 16 KB
  uint4* W2F8hi = (uint4*)(ws + (32 << 10));                 //  8 KB
  uint4* W2F8lo = (uint4*)(ws + (40 << 10));                 //  8 KB
  u16*   vh1 = (u16*)(ws + (64 << 10));                      // 512 KB [b][r][256] f16 (v1)
  u16*   vh2 = (u16*)(ws + (64 << 10) + (512 << 10));        // 512 KB [b][c][256] f16 (v2)
  u16*   ms1 = (u16*)(ws + (64 << 10) + (4 << 20));          //  16 MB [b][h][r][c]
  u16*   ms2 = (u16*)(ws + (64 << 10) + (20 << 20));         //  16 MB [b][h][c][r]
  char*  tail= (ws + (64 << 10) + (36 << 20));
  uint4* QQ4  = (uint4*)(tail);                              //   1 MB
  uint4* KH4  = (uint4*)(tail + (1 << 20));                  // 0.5 MB
  uint4* KL4z = (uint4*)(tail + (1 << 20) + (512 << 10));    //   1 MB
  float* o1  = (float*)(tail + (3 << 20));                   //   1 MB [b][r][256]
  float* o2  = (float*)(tail + (4 << 20));                   //   1 MB [b][c][256]

  gemm_mf_pack<<<dim3(32, 33), 256, 0, stream>>>(x1, Wqv1, vh1, x2, Wkv2, vh2,
                                                 W1, W2, QQ4, KH4, KL4z,
                                                 W1F8hi, W1F8lo, W2F8hi, W2F8lo);

  ms_mfma8b<<<dim3(32, 16, 2), 256, 0, stream>>>(QQ4, KH4, KL4z, cost,
                                                 W1F8hi, W1F8lo, W2F8hi, W2F8lo, ms1, ms2);

  softmax_all5b<<<dim3(256, 2, 2), 256, 0, stream>>>(ms1, ms2, attn, vh1, vh2, o1, o2);

  gemm_mf<<<dim3(16, 32), 256, 0, stream>>>(o1, Wout1, out, o2, Wout2, out + (size_t)262144, 256, 256);
}

// Round 19
// 156.760 us; speedup vs baseline: 1.2506x; 1.0164x over previous
//
#include <hip/hip_runtime.h>
#include <hip/hip_bf16.h>

typedef unsigned int   u32;
typedef unsigned short u16;

typedef __attribute__((ext_vector_type(8))) short    sh8;
typedef __attribute__((ext_vector_type(4))) float    f32x4;
typedef __attribute__((ext_vector_type(8))) _Float16 f16x8;
typedef __attribute__((ext_vector_type(2))) _Float16 f16x2;
typedef __attribute__((ext_vector_type(2))) __fp16   fp16x2raw;

union F16x8 { f16x8 v; uint4 u; f16x2 p[4]; _Float16 h[8]; };
union F16x4u { uint2 u; _Float16 h[4]; };
union F16x2u { u32 u; _Float16 h[2]; };
union CvtU  { fp16x2raw r; f16x2 p; u32 u; };

__device__ __forceinline__ float b2f(u16 u) { union { u32 i; float f; } v; v.i = ((u32)u) << 16; return v.f; }
__device__ __forceinline__ u16   f2b(float f){
  union { float f; u32 i; } v; v.f = f;
  u32 u = v.i;
  u32 r = (u + 0x7fffu + ((u >> 16) & 1u)) >> 16;   // RNE
  return (u16)r;
}
// pack two f32 -> bf16x2 (RNE), lo half = a, hi half = b
__device__ __forceinline__ u32 pk2(float a, float b) {
  __hip_bfloat162 h2 = __float22bfloat162_rn(make_float2(a, b));
  union { __hip_bfloat162 h; u32 u; } v; v.h = h2; return v.u;
}
__device__ __forceinline__ f16x2 cvtpk(float a, float b) {
  CvtU c; c.r = __builtin_amdgcn_cvt_pkrtz(a, b); return c.p;
}
__device__ __forceinline__ u32 cvtpku(float a, float b) {
  CvtU c; c.r = __builtin_amdgcn_cvt_pkrtz(a, b); return c.u;
}

__device__ __forceinline__ f32x4 mfma16(uint4 a, uint4 b, f32x4 c) {
  union { uint4 u; sh8 s; } ua, ub;
  ua.u = a; ub.u = b;
  return __builtin_amdgcn_mfma_f32_16x16x32_bf16(ua.s, ub.s, c, 0, 0, 0);
}
__device__ __forceinline__ f32x4 mfma32h(f16x8 a, f16x8 b, f32x4 c) {
  return __builtin_amdgcn_mfma_f32_16x16x32_f16(a, b, c, 0, 0, 0);
}

// split 8 consecutive f32 (one lane's K-chunk) into bf16 hi/lo operand words
__device__ __forceinline__ void split8(float4 v0, float4 v1, uint4& hi, uint4& lo) {
  float a[8] = {v0.x, v0.y, v0.z, v0.w, v1.x, v1.y, v1.z, v1.w};
  u32 hw[4], lw[4];
#pragma unroll
  for (int t = 0; t < 4; t++) {
    u32 hp = pk2(a[2 * t], a[2 * t + 1]);
    float r0 = a[2 * t]     - __uint_as_float(hp << 16);
    float r1 = a[2 * t + 1] - __uint_as_float(hp & 0xffff0000u);
    hw[t] = hp;
    lw[t] = pk2(r0, r1);
  }
  hi = make_uint4(hw[0], hw[1], hw[2], hw[3]);
  lo = make_uint4(lw[0], lw[1], lw[2], lw[3]);
}

// ---------------------------------------------------------------------------
// gemm_mf: two independent C = A @ B^T f32 GEMMs via MFMA (sel = by>>4).
// One wave per 16x16 C tile.  Used for the output projections (N=256, K=256).
// ---------------------------------------------------------------------------
__global__ void __launch_bounds__(256)
gemm_mf(const float* __restrict__ A0, const float* __restrict__ B0, float* __restrict__ C0,
        const float* __restrict__ A1, const float* __restrict__ B1, float* __restrict__ C1,
        int N, int K) {
  int t = threadIdx.x, L = t & 63, w = t >> 6;
  int cl = L & 15, q = L >> 4;
  int by = blockIdx.y, sel = by >> 4;
  const float* A  = sel ? A1 : A0;
  const float* Bw = sel ? B1 : B0;
  float*       C  = sel ? C1 : C0;
  int m0 = (by & 15) * 64 + w * 16;
  int n0 = blockIdx.x * 16;

  f32x4 acc; acc[0] = 0.f; acc[1] = 0.f; acc[2] = 0.f; acc[3] = 0.f;
  const float* ar = A  + (size_t)(m0 + cl) * K + 8 * q;
  const float* br = Bw + (size_t)(n0 + cl) * K + 8 * q;

  for (int k0 = 0; k0 < K; k0 += 32) {
    float4 av0 = *(const float4*)(ar + k0);
    float4 av1 = *(const float4*)(ar + k0 + 4);
    float4 bv0 = *(const float4*)(br + k0);
    float4 bv1 = *(const float4*)(br + k0 + 4);
    uint4 ahi, alo, bhi, blo;
    split8(av0, av1, ahi, alo);
    split8(bv0, bv1, bhi, blo);
    acc = mfma16(ahi, bhi, acc);
    acc = mfma16(ahi, blo, acc);
    acc = mfma16(alo, bhi, acc);
  }
#pragma unroll
  for (int i = 0; i < 4; i++)
    C[(size_t)(m0 + 4 * q + i) * N + n0 + cl] = acc[i];
}

// ---------------------------------------------------------------------------
// gemm_mf_pack: QKV projections (N=512, K=256) with FUSED fragment packing.
// by<32: gemm.  n0>=256 -> V stored f16 [b][row][256] (via Ld transpose).
// n0<256 (h = bx): Q/K tile transposed in per-wave LDS, emitted as frags.
// by==32, bx<8: W1 (f16x8 hi A-operand) + W2 (f16x8 paired-nt) packing.
// ---------------------------------------------------------------------------
__global__ void __launch_bounds__(256)
gemm_mf_pack(const float* __restrict__ x1, const float* __restrict__ Wqv1, u16* __restrict__ vh1,
             const float* __restrict__ x2, const float* __restrict__ Wkv2, u16* __restrict__ vh2,
             const float* __restrict__ W1, const float* __restrict__ W2,
             uint4* __restrict__ QQ4, uint4* __restrict__ KH4, uint4* __restrict__ KL4z,
             uint4* __restrict__ W1F8hi, uint4* __restrict__ W1F8lo,
             uint4* __restrict__ W2F8hi, uint4* __restrict__ W2F8lo) {
  __shared__ float Ld[4][16][17];
  int t = threadIdx.x, L = t & 63, w = t >> 6;
  int cl = L & 15, q = L >> 4;
  int by = blockIdx.y;

  if (by == 32) {                       // ---- W packing blocks ----
    if (blockIdx.x >= 8) return;
    int tid = blockIdx.x * 256 + t;     // 0..2047
    if (tid < 1024) {
      // W1 A-operand f16 hi/lo: nt = tid>>6; lane L: m=j=nt*16+(L&15), k=8q+jj
      int LL = tid & 63, nt = tid >> 6;
      int j = nt * 16 + (LL & 15), qq = LL >> 4;
      F16x8 hi, lo;
#pragma unroll
      for (int jj = 0; jj < 8; jj++) {
        float wv = W1[j * 32 + qq * 8 + jj];
        hi.h[jj] = (_Float16)wv;
        lo.h[jj] = (_Float16)(wv - (float)hi.h[jj]);
      }
      W1F8hi[tid] = hi.u;
      W1F8lo[tid] = lo.u;
    } else if (tid < 1536) {
      int t2 = tid - 1024;              // p*64 + L
      int LL = t2 & 63, p = t2 >> 6;
      int h = LL & 15, qq = LL >> 4;
      F16x8 hi, lo;
#pragma unroll
      for (int jj = 0; jj < 8; jj++) {
        int j = 32 * p + ((jj >> 2) << 4) + 4 * qq + (jj & 3);
        float wv = W2[h * 256 + j];
        hi.h[jj] = (_Float16)wv;
        lo.h[jj] = (_Float16)(wv - (float)hi.h[jj]);
      }
      W2F8hi[t2] = hi.u;
      W2F8lo[t2] = lo.u;
    }
    return;
  }

  int sel = by >> 4;
  const float* A  = sel ? x2 : x1;
  const float* Bw = sel ? Wkv2 : Wqv1;
  int m0 = (by & 15) * 64 + w * 16;
  int n0 = blockIdx.x * 16;

  f32x4 acc; acc[0] = 0.f; acc[1] = 0.f; acc[2] = 0.f; acc[3] = 0.f;
  const float* ar = A  + (size_t)(m0 + cl) * 256 + 8 * q;
  const float* br = Bw + (size_t)(n0 + cl) * 256 + 8 * q;

  for (int k0 = 0; k0 < 256; k0 += 32) {
    float4 av0 = *(const float4*)(ar + k0);
    float4 av1 = *(const float4*)(ar + k0 + 4);
    float4 bv0 = *(const float4*)(br + k0);
    float4 bv1 = *(const float4*)(br + k0 + 4);
    uint4 ahi, alo, bhi, blo;
    split8(av0, av1, ahi, alo);
    split8(bv0, bv1, bhi, blo);
    acc = mfma16(ahi, bhi, acc);
    acc = mfma16(ahi, blo, acc);
    acc = mfma16(alo, bhi, acc);
  }

  int b = m0 >> 9;
  int row = (m0 & 511) + cl;            // r (or c) index after transpose

  if (n0 >= 256) {                      // ---- V half: f16 store via transpose ----
#pragma unroll
    for (int i = 0; i < 4; i++) Ld[w][cl][4 * q + i] = acc[i];
    if (q < 2) {
      float v[8];
#pragma unroll
      for (int jj = 0; jj < 8; jj++) v[jj] = Ld[w][q * 8 + jj][cl];
      uint4 o = make_uint4(cvtpku(v[0], v[1]), cvtpku(v[2], v[3]),
                           cvtpku(v[4], v[5]), cvtpku(v[6], v[7]));
      u16* vh = sel ? vh2 : vh1;
      *(uint4*)(vh + ((size_t)(b * 512) + row) * 256 + (n0 - 256) + q * 8) = o;
    }
    return;
  }

  // ---- Q/K half: per-wave 16x16 transpose, then fragment emit ----
#pragma unroll
  for (int i = 0; i < 4; i++) Ld[w][cl][4 * q + i] = acc[i];   // Ld[d][r_local]
  float v[8];
#pragma unroll
  for (int jj = 0; jj < 8; jj++) v[jj] = Ld[w][(q & 1) * 8 + jj][cl];

  int r = row;
  int h = n0 >> 4;                      // == blockIdx.x

  if (sel == 0) {                       // Q: x0.25 folded; q<2 hi, q>=2 lo
    u32 wv[4];
#pragma unroll
    for (int t2 = 0; t2 < 4; t2++) {
      float a  = v[2 * t2] * 0.25f, bb = v[2 * t2 + 1] * 0.25f;
      u32 hp = pk2(a, bb);
      if (q >= 2) {
        float r0 = a  - __uint_as_float(hp << 16);
        float r1 = bb - __uint_as_float(hp & 0xffff0000u);
        wv[t2] = pk2(r0, r1);
      } else wv[t2] = hp;
    }
    QQ4[((size_t)((b * 16 + h) * 4 + q) << 9) + r] = make_uint4(wv[0], wv[1], wv[2], wv[3]);
  } else {                              // K: hi + lo + zero slots
    u32 hw[4], lw[4];
#pragma unroll
    for (int t2 = 0; t2 < 4; t2++) {
      float a = v[2 * t2], bb = v[2 * t2 + 1];
      u32 hp = pk2(a, bb);
      float r0 = a  - __uint_as_float(hp << 16);
      float r1 = bb - __uint_as_float(hp & 0xffff0000u);
      hw[t2] = hp;
      lw[t2] = pk2(r0, r1);
    }
    if (q < 2) {
      KH4[((size_t)((b * 16 + h) * 2 + q) << 9) + r]       = make_uint4(hw[0], hw[1], hw[2], hw[3]);
      KL4z[((size_t)((b * 16 + h) * 4 + 2 + q) << 9) + r]  = make_uint4(0, 0, 0, 0);
    } else {
      KL4z[((size_t)((b * 16 + h) * 4 + (q - 2)) << 9) + r] = make_uint4(lw[0], lw[1], lw[2], lw[3]);
    }
  }
}

// ---------------------------------------------------------------------------
// ms_mfma8c: ms_mfma8b with layer-1 W1-lo correction DROPPED (precision
// budget: adds ~2e-3 logit noise in quadrature with the dominant ~4e-3 bf16
// ms-storage noise; measured headroom 2x).  4 MFMAs per (p,r): layer1 hi for
// both nt groups + fused K=32 layer2 hi and lo.  Phase A (exact bf16 hi/lo
// QK, deduplicated across wave pairs) unchanged.
// ---------------------------------------------------------------------------
__global__ void __launch_bounds__(256, 4)
ms_mfma8c(const uint4* __restrict__ QQ4, const uint4* __restrict__ KH4,
          const uint4* __restrict__ KL4z, const float* __restrict__ cost,
          const uint4* __restrict__ W1F8hi, const uint4* __restrict__ W1F8lo,
          const uint4* __restrict__ W2F8hi, const uint4* __restrict__ W2F8lo,
          u16* __restrict__ ms1, u16* __restrict__ ms2) {
  __shared__ __align__(16) u32 Dl[2 * 2176];   // per wave-pair [16r][8hp][17]
  int t = threadIdx.x, L = t & 63, w = t >> 6;
  int cl = L & 15, q = L >> 4;
  int b = blockIdx.z, c0 = blockIdx.x * 16;
  int pairId = w >> 1, wl = w & 1;
  int r0a = blockIdx.y * 32 + pairId * 16;     // 16-aligned shared tile base
  int r0  = r0a + wl * 8;                      // this wave's 8 output rows
  u32* D = Dl + pairId * 2176;

  f32x4 z; z[0] = 0.f; z[1] = 0.f; z[2] = 0.f; z[3] = 0.f;

  // ---- phase A: 4 head-pairs per wave (hp = wl*4 + i), full 16-row tile ----
#pragma unroll 2
  for (int hpi = 0; hpi < 4; hpi++) {
    int hp = wl * 4 + hpi;
    int h0 = 2 * hp, h1 = 2 * hp + 1;
    uint4 qa  = QQ4[((size_t)((b * 16 + h0) * 4 + q) << 9) + r0a + cl];
    uint4 qa2 = QQ4[((size_t)((b * 16 + h0) * 4 + (q & 1)) << 9) + r0a + cl];
    uint4 kb1 = KH4[((size_t)((b * 16 + h0) * 2 + (q & 1)) << 9) + c0 + cl];
    uint4 kb2 = KL4z[((size_t)((b * 16 + h0) * 4 + q) << 9) + c0 + cl];
    f32x4 d0 = mfma16(qa, kb1, z);
    d0 = mfma16(qa2, kb2, d0);
    uint4 qb  = QQ4[((size_t)((b * 16 + h1) * 4 + q) << 9) + r0a + cl];
    uint4 qb2 = QQ4[((size_t)((b * 16 + h1) * 4 + (q & 1)) << 9) + r0a + cl];
    uint4 kc1 = KH4[((size_t)((b * 16 + h1) * 2 + (q & 1)) << 9) + c0 + cl];
    uint4 kc2 = KL4z[((size_t)((b * 16 + h1) * 4 + q) << 9) + c0 + cl];
    f32x4 d1 = mfma16(qb, kc1, z);
    d1 = mfma16(qb2, kc2, d1);
#pragma unroll
    for (int i = 0; i < 4; i++)
      D[(4 * q + i) * 136 + hp * 17 + cl] = cvtpku(d0[i], d1[i]);
  }
  __syncthreads();

  // ---- phase A2: build X f16x8 fragments (once), kept in registers ----
  F16x8 xv[8];
#pragma unroll
  for (int rr = 0; rr < 8; rr++) {
    int rl = wl * 8 + rr;
    float cv = cost[((size_t)(b * 512) + r0 + rr) * 512 + c0 + cl];
    u32 ch = cvtpku(0.f, cv);                  // cost f16 in high half
    u32 ua = D[rl * 136 + (2 * q) * 17 + cl];
    u32 ub = D[rl * 136 + (2 * q + 1) * 17 + cl];
    xv[rr].u = make_uint4((ua & 0xffffu) | ch, (ua >> 16) | ch,
                          (ub & 0xffffu) | ch, (ub >> 16) | ch);
  }

  // ---- phase B: p-outer MLP, 4 MFMAs per (p,r), zero LDS ----
  f32x4 acc2[8];
#pragma unroll
  for (int rr = 0; rr < 8; rr++) acc2[rr] = z;

#pragma unroll 1
  for (int p = 0; p < 8; p++) {
    F16x8 w1h0, w1h1, w2h, w2l;
    w1h0.u = W1F8hi[(2 * p) * 64 + L];
    w1h1.u = W1F8hi[(2 * p + 1) * 64 + L];
    w2h.u  = W2F8hi[p * 64 + L];
    w2l.u  = W2F8lo[p * 64 + L];
#pragma unroll
    for (int rr = 0; rr < 8; rr++) {
      f32x4 a0 = mfma32h(w1h0.v, xv[rr].v, z);
      f32x4 a1 = mfma32h(w1h1.v, xv[rr].v, z);
      F16x8 hf;
      hf.p[0] = cvtpk(fmaxf(a0[0], 0.f), fmaxf(a0[1], 0.f));
      hf.p[1] = cvtpk(fmaxf(a0[2], 0.f), fmaxf(a0[3], 0.f));
      hf.p[2] = cvtpk(fmaxf(a1[0], 0.f), fmaxf(a1[1], 0.f));
      hf.p[3] = cvtpk(fmaxf(a1[2], 0.f), fmaxf(a1[3], 0.f));
      acc2[rr] = mfma32h(hf.v, w2h.v, acc2[rr]);
      acc2[rr] = mfma32h(hf.v, w2l.v, acc2[rr]);
    }
  }

  // ---- epilogue: lane (q,cl) holds MS[h=cl][c=c0+4q+i][r0..r0+7] ----
  u32* ms1u = (u32*)ms1;
#pragma unroll
  for (int rr = 0; rr < 8; rr++) {
    size_t base = ((size_t)(b * 16 + cl) * 512 + (r0 + rr)) * 256 + (c0 >> 1) + q * 2;
    ms1u[base]     = pk2(acc2[rr][0], acc2[rr][1]);
    ms1u[base + 1] = pk2(acc2[rr][2], acc2[rr][3]);
  }
  u32* ms2u = (u32*)ms2;
#pragma unroll
  for (int i = 0; i < 4; i++) {
    int c = c0 + 4 * q + i;
    u32 o[4];
#pragma unroll
    for (int j = 0; j < 4; j++)
      o[j] = pk2(acc2[2 * j][i], acc2[2 * j + 1][i]);
    size_t base2 = ((size_t)(b * 16 + cl) * 512 + c) * 256 + (r0 >> 1);
    *(uint4*)&ms2u[base2] = make_uint4(o[0], o[1], o[2], o[3]);
  }
}

// ---------------------------------------------------------------------------
// softmax_all5b: 2 fixes per block (R16 champion, verbatim).
// ---------------------------------------------------------------------------
__global__ void __launch_bounds__(256)
softmax_all5b(const u16* __restrict__ ms1s, const u16* __restrict__ ms2s,
              const int* __restrict__ mask,
              const u16* __restrict__ vh1, const u16* __restrict__ vh2,
              float* __restrict__ o1, float* __restrict__ o2) {
  __shared__ _Float16 pbuf[512 * 16 * 2];   // 32 KB
  __shared__ float    sden[2][16];
  __shared__ float4   red[4][64];
  int t = threadIdx.x, lane = t & 63, w = t >> 6;
  int fix0 = blockIdx.x * 2, b = blockIdx.y, dir = blockIdx.z;
  const u16* ms   = dir ? ms2s : ms1s;
  const u16* vbuf = dir ? vh1 : vh2;
  float*     obuf = dir ? o2 : o1;

  int fsel = w >> 1;
  int fix  = fix0 + fsel;
  int hbase = (w & 1) * 8;
  bool vd[8];
#pragma unroll
  for (int i = 0; i < 8; i++) {
    int cc = i * 64 + lane;
    int mv = dir ? mask[((size_t)b * 512 + cc) * 512 + fix]
                 : mask[((size_t)b * 512 + fix) * 512 + cc];
    vd[i] = mv != 0;
  }
  bool anyl = false;
#pragma unroll
  for (int i = 0; i < 8; i++) anyl |= vd[i];
  bool useMask = (__ballot(anyl) != 0ULL);   // fully-masked row => unmask all

#pragma unroll 2
  for (int h2 = 0; h2 < 8; h2++) {
    int h = hbase + h2;
    const u16* mrow = ms + ((size_t)(b * 16 + h) * 512 + fix) * 512;
    float lg[8];
#pragma unroll
    for (int i = 0; i < 8; i++) lg[i] = b2f(mrow[i * 64 + lane]);
    float mx = -3.4e38f;
#pragma unroll
    for (int i = 0; i < 8; i++)
      if (!(useMask && !vd[i])) mx = fmaxf(mx, lg[i]);
    for (int off = 32; off; off >>= 1) mx = fmaxf(mx, __shfl_xor(mx, off));
    float s = 0.f;
#pragma unroll
    for (int i = 0; i < 8; i++) {
      float p = (useMask && !vd[i]) ? 0.f : __expf(lg[i] - mx);
      int cc = i * 64 + lane;
      pbuf[(cc * 16 + ((h + cc) & 15)) * 2 + fsel] = (_Float16)p;
      s += p;
    }
    for (int off = 32; off; off >>= 1) s += __shfl_xor(s, off);
    if (lane == 0) sden[fsel][h] = s;
  }
  __syncthreads();

  int hb = lane >> 2, dq = lane & 3;
  const u16* vb = vbuf + (size_t)b * 131072 + hb * 16 + dq * 4;
  float4 acc0 = make_float4(0.f, 0.f, 0.f, 0.f);
  float4 acc1 = make_float4(0.f, 0.f, 0.f, 0.f);
  for (int it = 0; it < 128; it++) {
    int cc = it * 4 + w;
    F16x4u vv; vv.u = *(const uint2*)(vb + (size_t)cc * 256);
    F16x2u pv; pv.u = *(const u32*)&pbuf[(cc * 16 + ((hb + cc) & 15)) * 2];
    float v0 = (float)vv.h[0], v1 = (float)vv.h[1];
    float v2 = (float)vv.h[2], v3 = (float)vv.h[3];
    float p0 = (float)pv.h[0], p1 = (float)pv.h[1];
    acc0.x += p0 * v0; acc0.y += p0 * v1; acc0.z += p0 * v2; acc0.w += p0 * v3;
    acc1.x += p1 * v0; acc1.y += p1 * v1; acc1.z += p1 * v2; acc1.w += p1 * v3;
  }
#pragma unroll 1
  for (int f = 0; f < 2; f++) {
    red[w][lane] = f ? acc1 : acc0;
    __syncthreads();
    if (w == 0) {
      float4 s0 = red[0][lane], s1 = red[1][lane];
      float4 s2 = red[2][lane], s3 = red[3][lane];
      float inv = 1.f / sden[f][hb];
      float4 o;
      o.x = (s0.x + s1.x + s2.x + s3.x) * inv;
      o.y = (s0.y + s1.y + s2.y + s3.y) * inv;
      o.z = (s0.z + s1.z + s2.z + s3.z) * inv;
      o.w = (s0.w + s1.w + s2.w + s3.w) * inv;
      *(float4*)(obuf + ((size_t)b * 512 + fix0 + f) * 256 + lane * 4) = o;
    }
    __syncthreads();
  }
}

// ---------------------------------------------------------------------------
extern "C" void kernel_launch(void* const* d_in, const int* in_sizes, int n_in,
                              void* d_out, int out_size, void* d_ws, size_t ws_size,
                              hipStream_t stream) {
  const float* x1    = (const float*)d_in[0];
  const float* x2    = (const float*)d_in[1];
  const int*   attn  = (const int*)d_in[2];
  const float* cost  = (const float*)d_in[3];
  const float* Wqv1  = (const float*)d_in[4];
  const float* Wkv2  = (const float*)d_in[5];
  const float* W1    = (const float*)d_in[6];
  const float* W2    = (const float*)d_in[7];
  const float* Wout1 = (const float*)d_in[8];
  const float* Wout2 = (const float*)d_in[9];
  float* out = (float*)d_out;

  char* ws = (char*)d_ws;
  uint4* W1F8hi = (uint4*)(ws);                              // 16 KB
  uint4* W1F8lo = (uint4*)(ws + (16 << 10));                 // 16 KB
  uint4* W2F8hi = (uint4*)(ws + (32 << 10));                 //  8 KB
  uint4* W2F8lo = (uint4*)(ws + (40 << 10));                 //  8 KB
  u16*   vh1 = (u16*)(ws + (64 << 10));                      // 512 KB [b][r][256] f16 (v1)
  u16*   vh2 = (u16*)(ws + (64 << 10) + (512 << 10));        // 512 KB [b][c][256] f16 (v2)
  u16*   ms1 = (u16*)(ws + (64 << 10) + (4 << 20));          //  16 MB [b][h][r][c]
  u16*   ms2 = (u16*)(ws + (64 << 10) + (20 << 20));         //  16 MB [b][h][c][r]
  char*  tail= (ws + (64 << 10) + (36 << 20));
  uint4* QQ4  = (uint4*)(tail);                              //   1 MB
  uint4* KH4  = (uint4*)(tail + (1 << 20));                  // 0.5 MB
  uint4* KL4z = (uint4*)(tail + (1 << 20) + (512 << 10));    //   1 MB
  float* o1  = (float*)(tail + (3 << 20));                   //   1 MB [b][r][256]
  float* o2  = (float*)(tail + (4 << 20));                   //   1 MB [b][c][256]

  gemm_mf_pack<<<dim3(32, 33), 256, 0, stream>>>(x1, Wqv1, vh1, x2, Wkv2, vh2,
                                                 W1, W2, QQ4, KH4, KL4z,
                                                 W1F8hi, W1F8lo, W2F8hi, W2F8lo);

  ms_mfma8c<<<dim3(32, 16, 2), 256, 0, stream>>>(QQ4, KH4, KL4z, cost,
                                                 W1F8hi, W1F8lo, W2F8hi, W2F8lo, ms1, ms2);

  softmax_all5b<<<dim3(256, 2, 2), 256, 0, stream>>>(ms1, ms2, attn, vh1, vh2, o1, o2);

  gemm_mf<<<dim3(16, 32), 256, 0, stream>>>(o1, Wout1, out, o2, Wout2, out + (size_t)262144, 256, 256);
}